// Round 7
// baseline (5596.888 us; speedup 1.0000x reference)
//
#include <hip/hip_runtime.h>
#include <hip/hip_bf16.h>
#include <math.h>

// ---------------- problem constants ----------------
#define Bsz 512
#define Tin 96
#define DIN 64
#define Hd  256
#define Pp  2
#define Ll  4
#define NHEAD 8
#define Ed  768          // 3*H
#define NCls 100
#define Tp  48           // T/P tokens after patch
#define Ff  25           // rfft freqs of 48
#define F2  13           // rfft freqs of 25
#define DH  96           // E / HEADS

// epilogue flags
#define E_BIAS 1
#define E_PE   2
#define E_RES  4
#define E_ACC  8
#define E_GELU 16
#define E_OUTS 32        // write split hi/lo bf16 planes
#define E_SPLK 64        // split-K: atomicAdd partials into C

typedef unsigned short ushortT;
typedef unsigned short ushort8 __attribute__((ext_vector_type(8)));
typedef short short8 __attribute__((ext_vector_type(8)));
typedef float f32x4 __attribute__((ext_vector_type(4)));

static __device__ __forceinline__ ushortT f2bf(float f) {
  __hip_bfloat16 h = __float2bfloat16(f);
  return *reinterpret_cast<ushortT*>(&h);
}
static __device__ __forceinline__ float bfbits2f(ushortT u) {
  unsigned int x = ((unsigned int)u) << 16;
  return __uint_as_float(x);
}
static __device__ __forceinline__ void split2(float v, ushortT& h, ushortT& l) {
  h = f2bf(v);
  l = f2bf(v - bfbits2f(h));
}

// async global->LDS, 16B per lane; LDS dest is wave-uniform base + lane*16,
// global src is per-lane (lets us pre-swizzle the source for a swizzled layout).
typedef const __attribute__((address_space(1))) void* gas1_t;
typedef __attribute__((address_space(3))) void* las3_t;
static __device__ __forceinline__ void gload16(const void* g, void* l) {
  __builtin_amdgcn_global_load_lds((gas1_t)g, (las3_t)l, 16, 0, 0);
}

// =================== bf16x3 split MFMA GEMM ===================
// AMODE: 0 plain; 1 diff along Tdim; 2 tap-major conv (K=(tap,i), Kin inner)
// ASRC:  0 A fp32 [M,K]; 1 A pre-split planes Ah/Al [M,K] bf16
// BMS:   M-tile select (128 or 64). GBN=128, GBK=32, 256 thr / 4 waves.
//
// ASRC=1 K-loop (R7): T4 counted-vmcnt double-buffered pipeline.
//   stage(buf^1, tile s+1) -> s_waitcnt vmcnt(NL) [NL = loads just issued;
//   waits only tile-s's OLDER loads, tile-s+1's stay in flight] -> barrier
//   -> ds_read+MFMA on buf -> barrier. vmcnt(0) only at the last step.
//   R1-R6 measured: the old per-step vmcnt(0) drain pinned achieved HBM BW
//   at ~870 GB/s (time == bytes/870GB/s across all tile configs); counted
//   vmcnt is the m218-proven fix (drain-0 pipelining = no gain, R2).
// ASRC=0 K-loop: proven single-buffer __syncthreads drain (reg loads in
//   A-staging would pollute the vmcnt count).
// XOR swizzle byte^(((row>>1)&3)<<4): pre-swizzled global source, linear
// LDS dest, swizzled ds_read (conflict-free, measured 0 since R1).
constexpr int GBN = 128, GBK = 32;

template<int BMS, int AMODE, int ASRC, int EPI>
__global__ __launch_bounds__(256) void gemm3(
    const float* __restrict__ A,
    const ushortT* __restrict__ Ah, const ushortT* __restrict__ Al,
    const ushortT* __restrict__ Bh, const ushortT* __restrict__ Bl,
    const float* __restrict__ bias, const float* __restrict__ extra,
    float* __restrict__ C, ushortT* __restrict__ Coh, ushortT* __restrict__ Col,
    int M, int N, int K, int Ald, int Tdim, int lo, int Kin, int Cld, int coff,
    int Mt, int Nt, int mmaj, int ksn)
{
  constexpr int GBMv = BMS;            // 128 or 64
  constexpr int WMF  = GBMv / 32;      // M-frags per wave: 4 or 2
  constexpr int ARPW = GBMv / 4;       // A rows staged per wave: 32 or 16
  constexpr int TPR  = 256 / GBMv;     // threads per A-row (ASRC0): 2 or 4
  constexpr int EPT  = 32 / TPR;       // shorts per thread (ASRC0): 16 or 8
  constexpr int NBUF = (ASRC == 1) ? 2 : 1;
  constexpr int APL  = GBMv * GBK;     // A plane shorts
  constexpr int BPL  = GBN * GBK;      // B plane shorts

  __shared__ __align__(16) ushortT Ash[NBUF * APL];
  __shared__ __align__(16) ushortT Asl[NBUF * APL];
  __shared__ __align__(16) ushortT Bsh[NBUF * BPL];
  __shared__ __align__(16) ushortT Bsl[NBUF * BPL];
  int tid = threadIdx.x;

  // ---- bijective XCD-aware swizzle over [0, G) ----
  int lin = blockIdx.x;
  int G = gridDim.x;
  int r8 = lin & 7, s8 = lin >> 3;
  int q = G >> 3, rem = G & 7;
  int start = r8 * q + (r8 < rem ? r8 : rem);
  int idx = start + s8;
  int tiles = Mt * Nt;
  int ks = 0;
  if (ksn > 1) { ks = idx / tiles; idx -= ks * tiles; }
  int mt, nt;
  if (mmaj) { mt = idx / Nt; nt = idx - mt * Nt; }
  else      { nt = idx / Mt; mt = idx - nt * Mt; }
  int m0 = mt * GBMv, n0 = nt * GBN;
  int kper = K / ksn;
  int kbeg = ks * kper, kend = kbeg + kper;

  int wid = tid >> 6, lane = tid & 63;
  int wm = wid & 1, wn = wid >> 1;       // 2 M-waves x 2 N-waves
  int m16 = lane & 15, quad = lane >> 4;

  f32x4 acc[WMF][4] = {};

  // ---- gload staging geometry ----
  int gcb = (lane & 3) << 4;                       // byte col within 64B row
  // B: 128 rows = 4 waves x 32 rows, 2 calls of 16 rows each per plane
  int growB = (wid << 5) + (lane >> 2);
  int scbB  = gcb ^ (((growB >> 1) & 3) << 4);     // swz(row+16)==swz(row)
  size_t bo0 = ((size_t)(n0 + growB) * K) * 2 + scbB;
  size_t bo1 = bo0 + (size_t)16 * K * 2;
  // A: GBMv rows = 4 waves x ARPW rows (1 or 2 calls per plane)
  int growA = wid * ARPW + (lane >> 2);
  int scbA  = gcb ^ (((growA >> 1) & 3) << 4);
  size_t ao0 = 0, ao1 = 0;
  if (ASRC == 1) {
    int ar0 = m0 + growA;  if (ar0 >= M) ar0 = M - 1;
    ao0 = ((size_t)ar0 * Ald) * 2 + scbA;
    if (ARPW == 32) {
      int ar1 = m0 + growA + 16;  if (ar1 >= M) ar1 = M - 1;
      ao1 = ((size_t)ar1 * Ald) * 2 + scbA;
    }
  }

  // ---- ASRC=0 compute-staging store addresses (swizzled, short-index) ----
  int srow = tid / TPR;                // 0..GBMv-1
  int sseg = (tid % TPR) * EPT;        // short offset within the 32-K row
  int sswz = ((srow >> 1) & 3) << 3;   // swizzle in short units (16B granule)

  // ---- fragment read addressing (same XOR) ----
  int fswz = ((m16 >> 1) & 3) << 3;
  int scf  = (quad << 3) ^ fswz;

  if constexpr (ASRC == 1) {
    // ======== counted-vmcnt double-buffered pipeline ========
    auto stageP = [&](int bsel, int k0) {
      size_t kb = (size_t)k0 * 2;
      char* lB = (char*)Bsh + bsel * (BPL * 2) + (wid << 11);
      char* lb = (char*)Bsl + bsel * (BPL * 2) + (wid << 11);
      gload16((const char*)Bh + bo0 + kb, lB);
      gload16((const char*)Bh + bo1 + kb, lB + 1024);
      gload16((const char*)Bl + bo0 + kb, lb);
      gload16((const char*)Bl + bo1 + kb, lb + 1024);
      char* lA = (char*)Ash + bsel * (APL * 2) + wid * ARPW * 64;
      char* la = (char*)Asl + bsel * (APL * 2) + wid * ARPW * 64;
      gload16((const char*)Ah + ao0 + kb, lA);
      gload16((const char*)Al + ao0 + kb, la);
      if constexpr (ARPW == 32) {
        gload16((const char*)Ah + ao1 + kb, lA + 1024);
        gload16((const char*)Al + ao1 + kb, la + 1024);
      }
    };
    int nsteps = (kend - kbeg) / GBK;
    stageP(0, kbeg);
    int cur = 0;
    for (int s = 0; s < nsteps; ++s) {
      if (s + 1 < nsteps) {
        stageP(cur ^ 1, kbeg + (s + 1) * GBK);
        // wait only the OLDER tile's loads; the NL just issued stay in flight
        if constexpr (GBMv == 128) asm volatile("s_waitcnt vmcnt(8)" ::: "memory");
        else                       asm volatile("s_waitcnt vmcnt(6)" ::: "memory");
      } else {
        asm volatile("s_waitcnt vmcnt(0)" ::: "memory");
      }
      __builtin_amdgcn_s_barrier();          // all waves' tile-s loads landed
      __builtin_amdgcn_sched_barrier(0);
      short8 ah[WMF], al[WMF], bh[4], bl[4];
      int ab = cur * APL, bb2 = cur * BPL;
#pragma unroll
      for (int i = 0; i < WMF; i++) {
        int ro = (wm * (WMF * 16) + i * 16 + m16) * GBK + scf;
        ah[i] = *(short8*)&Ash[ab + ro];
        al[i] = *(short8*)&Asl[ab + ro];
      }
#pragma unroll
      for (int j = 0; j < 4; j++) {
        int ro = (wn * 64 + j * 16 + m16) * GBK + scf;
        bh[j] = *(short8*)&Bsh[bb2 + ro];
        bl[j] = *(short8*)&Bsl[bb2 + ro];
      }
      __builtin_amdgcn_s_setprio(1);
#pragma unroll
      for (int i = 0; i < WMF; i++)
#pragma unroll
        for (int j = 0; j < 4; j++) {
          acc[i][j] = __builtin_amdgcn_mfma_f32_16x16x32_bf16(ah[i], bh[j], acc[i][j], 0, 0, 0);
          acc[i][j] = __builtin_amdgcn_mfma_f32_16x16x32_bf16(al[i], bh[j], acc[i][j], 0, 0, 0);
          acc[i][j] = __builtin_amdgcn_mfma_f32_16x16x32_bf16(ah[i], bl[j], acc[i][j], 0, 0, 0);
        }
      __builtin_amdgcn_s_setprio(0);
      __builtin_amdgcn_s_barrier();          // buf[cur] reads retired
      __builtin_amdgcn_sched_barrier(0);     // keep next stage below barrier
      cur ^= 1;
    }
  } else {
    // ======== proven single-buffer drain loop (compute-staged A) ========
    for (int k0 = kbeg; k0 < kend; k0 += GBK) {
      size_t kb = (size_t)k0 * 2;
      {
        char* ldsB = (char*)Bsh + (wid << 11);
        char* ldsb = (char*)Bsl + (wid << 11);
        gload16((const char*)Bh + bo0 + kb, ldsB);
        gload16((const char*)Bh + bo1 + kb, ldsB + 1024);
        gload16((const char*)Bl + bo0 + kb, ldsb);
        gload16((const char*)Bl + bo1 + kb, ldsb + 1024);
      }
      {
        int row = m0 + srow;
        if (row >= M) row = M - 1;
        float tf[EPT];
        if (AMODE == 0) {
          const float* p = A + (size_t)row * Ald + k0 + sseg;
#pragma unroll
          for (int j = 0; j < EPT; j += 4) {
            float4 v = *(const float4*)(p + j);
            tf[j] = v.x; tf[j+1] = v.y; tf[j+2] = v.z; tf[j+3] = v.w;
          }
        } else if (AMODE == 1) {
          int t = row % Tdim;
          const float* p = A + (size_t)row * Ald + k0 + sseg;
#pragma unroll
          for (int j = 0; j < EPT; j += 4) {
            float4 v = *(const float4*)(p + j);
            float4 w = (t != 0) ? *(const float4*)(p - Ald + j) : v;
            tf[j] = v.x - w.x; tf[j+1] = v.y - w.y;
            tf[j+2] = v.z - w.z; tf[j+3] = v.w - w.w;
          }
        } else {   // tap-major conv; tap uniform over this EPT-seg
          int kk = k0 + sseg;
          int tap = kk / Kin;
          int i0  = kk - tap * Kin;
          int bb = row / Tdim;
          int t  = row - bb * Tdim;
          int tt = t - lo + tap;
          if (tt >= 0 && tt < Tdim) {
            const float* p = A + ((size_t)bb * Tdim + tt) * Ald + i0;
#pragma unroll
            for (int j = 0; j < EPT; j += 4) {
              float4 v = *(const float4*)(p + j);
              tf[j] = v.x; tf[j+1] = v.y; tf[j+2] = v.z; tf[j+3] = v.w;
            }
          } else {
#pragma unroll
            for (int j = 0; j < EPT; j++) tf[j] = 0.0f;
          }
        }
        ushortT th[EPT], tl[EPT];
#pragma unroll
        for (int j = 0; j < EPT; j++) split2(tf[j], th[j], tl[j]);
#pragma unroll
        for (int c8 = 0; c8 < EPT / 8; c8++) {
          int st = srow * GBK + ((sseg + c8 * 8) ^ sswz);
          *(ushort8*)&Ash[st] = *(ushort8*)&th[c8 * 8];
          *(ushort8*)&Asl[st] = *(ushort8*)&tl[c8 * 8];
        }
      }
      __syncthreads();
      short8 ah[WMF], al[WMF], bh[4], bl[4];
#pragma unroll
      for (int i = 0; i < WMF; i++) {
        int ro = (wm * (WMF * 16) + i * 16 + m16) * GBK + scf;
        ah[i] = *(short8*)&Ash[ro];
        al[i] = *(short8*)&Asl[ro];
      }
#pragma unroll
      for (int j = 0; j < 4; j++) {
        int ro = (wn * 64 + j * 16 + m16) * GBK + scf;
        bh[j] = *(short8*)&Bsh[ro];
        bl[j] = *(short8*)&Bsl[ro];
      }
      __builtin_amdgcn_s_setprio(1);
#pragma unroll
      for (int i = 0; i < WMF; i++)
#pragma unroll
        for (int j = 0; j < 4; j++) {
          acc[i][j] = __builtin_amdgcn_mfma_f32_16x16x32_bf16(ah[i], bh[j], acc[i][j], 0, 0, 0);
          acc[i][j] = __builtin_amdgcn_mfma_f32_16x16x32_bf16(al[i], bh[j], acc[i][j], 0, 0, 0);
          acc[i][j] = __builtin_amdgcn_mfma_f32_16x16x32_bf16(ah[i], bl[j], acc[i][j], 0, 0, 0);
        }
      __builtin_amdgcn_s_setprio(0);
      __syncthreads();
    }
  }

  // ---- epilogue: C/D map col=lane&15, row=quad*4+r ----
#pragma unroll
  for (int i = 0; i < WMF; i++) {
#pragma unroll
    for (int j = 0; j < 4; j++) {
      int colg = n0 + wn * 64 + j * 16 + m16;
#pragma unroll
      for (int rr = 0; rr < 4; rr++) {
        int rowg = m0 + wm * (WMF * 16) + i * 16 + quad * 4 + rr;
        if (rowg >= M) continue;
        float v = acc[i][j][rr];
        if ((EPI & E_BIAS) && ks == 0) v += bias[colg];
        if (EPI & E_PE)   v += extra[(size_t)(rowg % Tdim) * N + colg];
        if (EPI & E_RES)  v += extra[(size_t)rowg * Cld + colg];
        if (EPI & E_GELU) v = 0.5f * v * (1.0f + erff(v * 0.70710678118654752f));
        size_t off = (size_t)rowg * Cld + coff + colg;
        if (EPI & E_SPLK) {
          atomicAdd(&C[off], v);
        } else if (EPI & E_OUTS) {
          ushortT h, l; split2(v, h, l);
          Coh[off] = h; Col[off] = l;
        } else {
          if (EPI & E_ACC) v += C[off];
          C[off] = v;
        }
      }
    }
  }
}

#define GEMM3(BMS_, AM, AS, EP, KS, Asrc, AhP, AlP, BhP, BlP, biasP, extraP, CP, CohP, ColP, \
              Mv, Nv, Kv, AldV, TdimV, loV, KinV, CldV, coffV) \
  do { int Mt_ = ((Mv) + (BMS_) - 1) / (BMS_), Nt_ = (Nv) / GBN; \
       int mm_ = ((Mv) >= (Nv)) ? 1 : 0; \
       gemm3<BMS_, AM, AS, EP><<<dim3(Mt_ * Nt_ * (KS)), dim3(256), 0, stream>>>( \
           Asrc, AhP, AlP, BhP, BlP, biasP, extraP, CP, CohP, ColP, \
           Mv, Nv, Kv, AldV, TdimV, loV, KinV, CldV, coffV, Mt_, Nt_, mm_, KS); } while (0)

// ====== weight transpose + split: fp32 [K][N] -> bf16 hi/lo [N][K] ======
__global__ __launch_bounds__(256) void wcvt_t_split(
    const float* __restrict__ W, ushortT* __restrict__ Wh, ushortT* __restrict__ Wl,
    int K, int N)
{
  __shared__ float t[32][33];
  int k0 = blockIdx.y * 32, n0 = blockIdx.x * 32;
  int tx = threadIdx.x;
  int ty = threadIdx.y;
#pragma unroll
  for (int dy = 0; dy < 32; dy += 8)
    t[ty + dy][tx] = W[(size_t)(k0 + ty + dy) * N + n0 + tx];
  __syncthreads();
#pragma unroll
  for (int dy = 0; dy < 32; dy += 8) {
    float v = t[tx][ty + dy];
    ushortT h, l;
    split2(v, h, l);
    size_t off = (size_t)(n0 + ty + dy) * K + k0 + tx;
    Wh[off] = h; Wl[off] = l;
  }
}

// ====== flat split: fp32 -> bf16 hi/lo ======
__global__ __launch_bounds__(256) void wcvt_split(
    const float* __restrict__ W, ushortT* __restrict__ Wh, ushortT* __restrict__ Wl, int n)
{
  int gid = blockIdx.x * 256 + threadIdx.x;
  int stride = gridDim.x * 256;
  for (int i = gid; i < n; i += stride) {
    ushortT h, l;
    split2(W[i], h, l);
    Wh[i] = h; Wl[i] = l;
  }
}

// ====== conv weight split, tap-major: [O][Kin][NT] -> [O][NT*Kin] ======
__global__ __launch_bounds__(256) void wcvt_split_tm(
    const float* __restrict__ W, ushortT* __restrict__ Wh, ushortT* __restrict__ Wl,
    int O, int Kin, int NT)
{
  int n = O * Kin * NT;
  int gid = blockIdx.x * 256 + threadIdx.x;
  int stride = gridDim.x * 256;
  for (int idx = gid; idx < n; idx += stride) {
    int o = idx / (Kin * NT);
    int rr = idx - o * (Kin * NT);
    int tap = rr / Kin;
    int i = rr - tap * Kin;
    float v = W[(size_t)o * Kin * NT + (size_t)i * NT + tap];
    ushortT h, l;
    split2(v, h, l);
    Wh[idx] = h; Wl[idx] = l;
  }
}

// =================== fp32 fallback GEMM (classifier only) ===================
constexpr int BM = 64, BN = 64, BK = 16, TM = 4, TN = 4;
__global__ __launch_bounds__(256) void gemm_cls(
    const float* __restrict__ A, const float* __restrict__ Bw,
    const float* __restrict__ bias, float* __restrict__ C,
    int M, int N, int K, int Ald, int Cld)
{
  __shared__ alignas(16) float As[BK][BM + 4];
  __shared__ alignas(16) float Bs[BK][BN + 4];
  int tid = threadIdx.x;
  int n0 = blockIdx.x * BN;
  int m0 = blockIdx.y * BM;
  int tx = tid & 15, ty = tid >> 4;
  float acc[TM][TN];
#pragma unroll
  for (int i = 0; i < TM; i++)
#pragma unroll
    for (int j = 0; j < TN; j++) acc[i][j] = 0.0f;
  int a_m = tid >> 2, a_k = (tid & 3) * 4;
  int b_k = tid >> 4, b_n = (tid & 15) * 4;
  for (int k0 = 0; k0 < K; k0 += BK) {
    int row = m0 + a_m;
#pragma unroll
    for (int j = 0; j < 4; j++)
      As[a_k + j][a_m] = A[(size_t)row * Ald + k0 + a_k + j];
    int kk = k0 + b_k;
#pragma unroll
    for (int j = 0; j < 4; j++) {
      int nn = n0 + b_n + j;
      Bs[b_k][b_n + j] = (nn < N) ? Bw[(size_t)kk * N + nn] : 0.0f;
    }
    __syncthreads();
#pragma unroll
    for (int k = 0; k < BK; k++) {
      float4 av = *reinterpret_cast<const float4*>(&As[k][ty * TM]);
      float4 bv = *reinterpret_cast<const float4*>(&Bs[k][tx * TN]);
      float a4[4] = {av.x, av.y, av.z, av.w};
      float b4[4] = {bv.x, bv.y, bv.z, bv.w};
#pragma unroll
      for (int i = 0; i < TM; i++)
#pragma unroll
        for (int j = 0; j < TN; j++) acc[i][j] += a4[i] * b4[j];
    }
    __syncthreads();
  }
#pragma unroll
  for (int i = 0; i < TM; i++) {
    int row = m0 + ty * TM + i;
#pragma unroll
    for (int j = 0; j < TN; j++) {
      int col = n0 + tx * TN + j;
      if (col >= N) continue;
      C[(size_t)row * Cld + col] = acc[i][j] + bias[col];
    }
  }
}

// ---- rfft over 48 tokens, real part (fp32) ----
__global__ __launch_bounds__(256) void rfft48_kernel(
    const float* __restrict__ hp, float* __restrict__ f)
{
  int kf = blockIdx.x;
  int b  = blockIdx.y;
  int tid = threadIdx.x;
  __shared__ float ct[48];
  if (tid < 48) {
    int rr = (kf * tid) % 48;
    ct[tid] = cosf(6.2831853071795864f * (float)rr / 48.0f);
  }
  __syncthreads();
  const float* hb = hp + (size_t)b * Tp * Hd;
  float s = 0.0f;
  for (int t = 0; t < 48; t++) s += hb[t * Hd + tid] * ct[t];
  f[((size_t)b * Ff + kf) * Hd + tid] = s;
}

// ---- fused fourier attention: logits -> softmax -> circulant(G) @ v ----
__global__ __launch_bounds__(256) void attn_fused(
    const float* __restrict__ qkv,     // chunk [nb*25, 2304]
    ushortT* __restrict__ oh, ushortT* __restrict__ ol)
{
  int bh = blockIdx.x;
  int b = bh >> 3, h = bh & 7;
  __shared__ float qs[Ff * DH], ks[Ff * DH], vs[Ff * DH];
  __shared__ float ct[F2 * Ff], st[F2 * Ff];
  __shared__ float red[F2 * DH];
  __shared__ float sm[F2];
  __shared__ float G[Ff];
  int tid = threadIdx.x;
  const float* base = qkv + (size_t)b * Ff * (3 * Ed) + h * DH;
  for (int e = tid; e < Ff * DH; e += 256) {
    int t = e / DH, d = e - t * DH;
    size_t ro = (size_t)t * (3 * Ed) + d;
    qs[e] = base[ro];
    ks[e] = base[ro + Ed];
    vs[e] = base[ro + 2 * Ed];
  }
  for (int e = tid; e < F2 * Ff; e += 256) {
    int fq = e / Ff, t = e - fq * Ff;
    int rr = (fq * t) % Ff;
    float ang = 6.2831853071795864f * (float)rr / 25.0f;
    ct[e] = cosf(ang); st[e] = sinf(ang);
  }
  __syncthreads();
  for (int e = tid; e < F2 * DH; e += 256) {
    int fq = e / DH, d = e - fq * DH;
    float qr = 0, qi = 0, kr = 0, ki = 0;
    for (int t = 0; t < Ff; t++) {
      float c = ct[fq * Ff + t], s = st[fq * Ff + t];
      float qv = qs[t * DH + d], kv = ks[t * DH + d];
      qr += qv * c; qi += qv * s; kr += kv * c; ki += kv * s;
    }
    red[e] = qr * kr + qi * ki;
  }
  __syncthreads();
  if (tid < F2) {
    float s = 0;
    for (int d = 0; d < DH; d++) s += red[tid * DH + d];
    sm[tid] = s * 0.10206207261596575f;  // 96^-0.5
  }
  __syncthreads();
  if (tid == 0) {
    float mx = sm[0];
    for (int f = 1; f < F2; f++) mx = fmaxf(mx, sm[f]);
    float den = 0;
    for (int f = 0; f < F2; f++) { float e2 = expf(sm[f] - mx); sm[f] = e2; den += e2; }
    float inv = 1.0f / den;
    for (int f = 0; f < F2; f++)
      sm[f] *= inv * ((f == 0) ? (1.0f / 25.0f) : (2.0f / 25.0f));
  }
  __syncthreads();
  if (tid < Ff) {
    float g = 0;
    for (int f = 0; f < F2; f++) g += sm[f] * ct[f * Ff + tid];
    G[tid] = g;
  }
  __syncthreads();
  size_t ob = ((size_t)b * Ff) * Ed + h * DH;
  for (int e = tid; e < Ff * DH; e += 256) {
    int t = e / DH, d = e - t * DH;
    float o = 0;
    int dd = t;
    for (int tp = 0; tp < Ff; tp++) {
      o += G[dd] * vs[tp * DH + d];
      dd--; if (dd < 0) dd += Ff;
    }
    ushortT hh, ll;
    split2(o, hh, ll);
    size_t off = ob + (size_t)t * Ed + d;
    oh[off] = hh; ol[off] = ll;
  }
}

// ---- layernorm over 768, split bf16 out ----
__global__ __launch_bounds__(256) void ln_split(
    const float* __restrict__ x, const float* __restrict__ g,
    const float* __restrict__ bb, ushortT* __restrict__ yh, ushortT* __restrict__ yl)
{
  int row = blockIdx.x;
  int tid = threadIdx.x;
  const float* xr = x + (size_t)row * Ed;
  float v0 = xr[tid], v1 = xr[tid + 256], v2 = xr[tid + 512];
  __shared__ float rs[256];
  rs[tid] = v0 + v1 + v2;
  __syncthreads();
  for (int o = 128; o > 0; o >>= 1) {
    if (tid < o) rs[tid] += rs[tid + o];
    __syncthreads();
  }
  float m = rs[0] * (1.0f / 768.0f);
  __syncthreads();
  float d0 = v0 - m, d1 = v1 - m, d2 = v2 - m;
  rs[tid] = d0 * d0 + d1 * d1 + d2 * d2;
  __syncthreads();
  for (int o = 128; o > 0; o >>= 1) {
    if (tid < o) rs[tid] += rs[tid + o];
    __syncthreads();
  }
  float inv = rsqrtf(rs[0] * (1.0f / 768.0f) + 1e-5f);
  size_t basei = (size_t)row * Ed;
  float o0 = d0 * inv * g[tid] + bb[tid];
  float o1 = d1 * inv * g[tid + 256] + bb[tid + 256];
  float o2 = d2 * inv * g[tid + 512] + bb[tid + 512];
  ushortT h, l;
  split2(o0, h, l); yh[basei + tid] = h;       yl[basei + tid] = l;
  split2(o1, h, l); yh[basei + tid + 256] = h; yl[basei + tid + 256] = l;
  split2(o2, h, l); yh[basei + tid + 512] = h; yl[basei + tid + 512] = l;
}

// ---- layernorm over 768, fp32 out (final) ----
__global__ __launch_bounds__(256) void ln_f32(
    const float* __restrict__ x, const float* __restrict__ g,
    const float* __restrict__ bb, float* __restrict__ y)
{
  int row = blockIdx.x;
  int tid = threadIdx.x;
  const float* xr = x + (size_t)row * Ed;
  float v0 = xr[tid], v1 = xr[tid + 256], v2 = xr[tid + 512];
  __shared__ float rs[256];
  rs[tid] = v0 + v1 + v2;
  __syncthreads();
  for (int o = 128; o > 0; o >>= 1) {
    if (tid < o) rs[tid] += rs[tid + o];
    __syncthreads();
  }
  float m = rs[0] * (1.0f / 768.0f);
  __syncthreads();
  float d0 = v0 - m, d1 = v1 - m, d2 = v2 - m;
  rs[tid] = d0 * d0 + d1 * d1 + d2 * d2;
  __syncthreads();
  for (int o = 128; o > 0; o >>= 1) {
    if (tid < o) rs[tid] += rs[tid + o];
    __syncthreads();
  }
  float inv = rsqrtf(rs[0] * (1.0f / 768.0f) + 1e-5f);
  float* yr = y + (size_t)row * Ed;
  yr[tid]       = d0 * inv * g[tid]       + bb[tid];
  yr[tid + 256] = d1 * inv * g[tid + 256] + bb[tid + 256];
  yr[tid + 512] = d2 * inv * g[tid + 512] + bb[tid + 512];
}

// ---- mean over 25 tokens ----
__global__ __launch_bounds__(256) void mean_kernel(
    const float* __restrict__ x, float* __restrict__ y)
{
  int b = blockIdx.x;
  int tid = threadIdx.x;
  for (int c = tid; c < Ed; c += 256) {
    float s = 0;
    for (int t = 0; t < Ff; t++) s += x[((size_t)b * Ff + t) * Ed + c];
    y[(size_t)b * Ed + c] = s * (1.0f / 25.0f);
  }
}

extern "C" void kernel_launch(void* const* d_in, const int* in_sizes, int n_in,
                              void* d_out, int out_size, void* d_ws, size_t ws_size,
                              hipStream_t stream)
{
  const float* x       = (const float*)d_in[0];
  const float* W_in    = (const float*)d_in[1];
  const float* b_in    = (const float*)d_in[2];
  const float* pe      = (const float*)d_in[3];
  const float* W_shape = (const float*)d_in[4];
  const float* b_shape = (const float*)d_in[5];
  const float* W_patch = (const float*)d_in[6];
  const float* b_patch = (const float*)d_in[7];
  const float* conv_w1 = (const float*)d_in[8];
  const float* conv_b1 = (const float*)d_in[9];
  const float* conv_w2 = (const float*)d_in[10];
  const float* conv_b2 = (const float*)d_in[11];
  const float* conv_w4 = (const float*)d_in[12];
  const float* conv_b4 = (const float*)d_in[13];
  const float* ln1_g   = (const float*)d_in[14];
  const float* ln1_b   = (const float*)d_in[15];
  const float* Wqkv    = (const float*)d_in[16];
  const float* Wo      = (const float*)d_in[17];
  const float* bo      = (const float*)d_in[18];
  const float* ln2_g   = (const float*)d_in[19];
  const float* ln2_b   = (const float*)d_in[20];
  const float* Wf1     = (const float*)d_in[21];
  const float* bf1     = (const float*)d_in[22];
  const float* Wf2     = (const float*)d_in[23];
  const float* bf2     = (const float*)d_in[24];
  const float* ssm_w   = (const float*)d_in[25];
  const float* ssm_b   = (const float*)d_in[26];
  const float* ssm_g   = (const float*)d_in[27];
  const float* ssm_bn  = (const float*)d_in[28];
  const float* W_out   = (const float*)d_in[29];
  const float* b_out   = (const float*)d_in[30];
  float* out = (float*)d_out;

  // ---- workspace: h 39.3MB | planes 39.3MB | pool 44.0MB = 122.7MB ----
  float* hbuf = (float*)d_ws;                    // 9,830,400 fl
  ushortT* Ahp = (ushortT*)(hbuf + 9830400);     // 9,830,400 slots
  ushortT* Alp = Ahp + 9830400;                  // 9,830,400 slots
  float* pool = (float*)(Alp + 9830400);         // 11,010,048 fl

  dim3 blk(256);
  dim3 wblk(32, 8);
  const int Mf = Bsz * Ff;   // 12800
  const ushortT* NUS = nullptr;
  const float* NF = nullptr;
  ushortT* NU = nullptr;

  // ---------------- phase-0 weights (pool + 6,291,456 fl) ----------------
  ushortT* p0w = (ushortT*)(pool + 6291456);
  ushortT* WinH = p0w + 0;        ushortT* WinL = p0w + 16384;
  ushortT* WshH = p0w + 32768;    ushortT* WshL = p0w + 98304;
  ushortT* WpaH = p0w + 163840;   ushortT* WpaL = p0w + 294912;
  ushortT* c1H  = p0w + 425984;   ushortT* c1L  = p0w + 491520;
  ushortT* c2H  = p0w + 557056;   ushortT* c2L  = p0w + 688128;
  ushortT* c4H  = p0w + 819200;   ushortT* c4L  = p0w + 1081344;
  wcvt_t_split<<<dim3(Hd / 32, DIN / 32), wblk, 0, stream>>>(W_in, WinH, WinL, DIN, Hd);
  wcvt_t_split<<<dim3(Hd / 32, Hd / 32), wblk, 0, stream>>>(W_shape, WshH, WshL, Hd, Hd);
  wcvt_t_split<<<dim3(Hd / 32, (Pp * Hd) / 32), wblk, 0, stream>>>(W_patch, WpaH, WpaL, Pp * Hd, Hd);
  wcvt_split<<<64, blk, 0, stream>>>(conv_w1, c1H, c1L, Hd * Hd);
  wcvt_split_tm<<<128, blk, 0, stream>>>(conv_w2, c2H, c2L, Hd, Hd, 2);
  wcvt_split_tm<<<256, blk, 0, stream>>>(conv_w4, c4H, c4L, Hd, Hd, 4);

  // ---------------- phase 0: 2 chunks of 256 batches ----------------
  float* s0  = (float*)Ahp;
  float* s1f = (float*)Ahp + 6291456;
  float* s1  = pool;
  for (int c = 0; c < 2; c++) {
    const int NB = 256;
    const int M96 = NB * Tin;      // 24576
    const int Mpch = NB * Tp;      // 12288
    const float* xc = x + (size_t)c * NB * Tin * DIN;

    GEMM3(64, 0, 0, E_BIAS | E_PE, 1, xc, NUS, NUS, WinH, WinL, b_in, pe, s0, NU, NU,
          M96, Hd, DIN, DIN, Tin, 0, 0, Hd, 0);
    GEMM3(64, 1, 0, E_BIAS | E_RES, 1, s0, NUS, NUS, WshH, WshL, b_shape, s0, s1, NU, NU,
          M96, Hd, Hd, Hd, Tin, 0, 0, Hd, 0);
    GEMM3(64, 0, 0, E_BIAS, 1, s1, NUS, NUS, WpaH, WpaL, b_patch, NF, s0, NU, NU,
          Mpch, Hd, Pp * Hd, Pp * Hd, 0, 0, 0, Hd, 0);
    rfft48_kernel<<<dim3(Ff, NB), blk, 0, stream>>>(s0, s1f + (size_t)c * NB * Ff * Hd);
  }
  // conv GEMMs over all 12800 rows at once
  GEMM3(64, 0, 0, E_BIAS, 1, s1f, NUS, NUS, c1H, c1L, conv_b1, NF, hbuf, NU, NU,
        Mf, Hd, Hd, Hd, Ff, 0, 0, Ed, 0);
  GEMM3(64, 2, 0, E_BIAS, 1, s1f, NUS, NUS, c2H, c2L, conv_b2, NF, hbuf, NU, NU,
        Mf, Hd, Hd * 2, Hd, Ff, 0, Hd, Ed, Hd);
  GEMM3(64, 2, 0, E_BIAS, 1, s1f, NUS, NUS, c4H, c4L, conv_b4, NF, hbuf, NU, NU,
        Mf, Hd, Hd * 4, Hd, Ff, 1, Hd, Ed, 2 * Hd);

  // ---------------- transformer layers ----------------
  float* qkvbuf = pool;                          // 7,372,800 fl (chunk 3200x2304)
  ushortT* lwA = (ushortT*)(pool + 7372800);
  ushortT* qkH = lwA + 0;        ushortT* qkL = lwA + 1769472;
  ushortT* woH = lwA + 3538944;  ushortT* woL = lwA + 4128768;
  ushortT* Ch2 = (ushortT*)pool;                 // ffmid hi (2048x3072)
  ushortT* Cl2 = Ch2 + 6291456;                  // ffmid lo
  ushortT* lwB = (ushortT*)(pool + 6291456);
  ushortT* f1H = lwB + 0;        ushortT* f1L = lwB + 2359296;
  ushortT* f2H = lwB + 4718592;  ushortT* f2L = lwB + 7077888;

  const int NBA = 128;           // batches per attention chunk (4 chunks)
  const int Mca = NBA * Ff;      // 3200 rows

  for (int l = 0; l < Ll; l++) {
    const float* Wqkv_l = Wqkv + (size_t)l * Ed * (3 * Ed);
    const float* Wo_l   = Wo   + (size_t)l * Ed * Ed;
    const float* bo_l   = bo   + (size_t)l * Ed;
    const float* Wf1_l  = Wf1  + (size_t)l * Ed * (4 * Ed);
    const float* bf1_l  = bf1  + (size_t)l * (4 * Ed);
    const float* Wf2_l  = Wf2  + (size_t)l * (4 * Ed) * Ed;
    const float* bf2_l  = bf2  + (size_t)l * Ed;

    wcvt_t_split<<<dim3((3 * Ed) / 32, Ed / 32), wblk, 0, stream>>>(Wqkv_l, qkH, qkL, Ed, 3 * Ed);
    wcvt_t_split<<<dim3(Ed / 32, Ed / 32), wblk, 0, stream>>>(Wo_l, woH, woL, Ed, Ed);

    ln_split<<<Mf, blk, 0, stream>>>(hbuf, ln1_g + (size_t)l * Ed, ln1_b + (size_t)l * Ed, Ahp, Alp);

    for (int c = 0; c < 4; c++) {
      ushortT* ah = Ahp + (size_t)c * Mca * Ed;
      ushortT* al = Alp + (size_t)c * Mca * Ed;
      GEMM3(64, 0, 1, 0, 1, NF, ah, al, qkH, qkL, NF, NF, qkvbuf, NU, NU,
            Mca, 3 * Ed, Ed, Ed, 0, 0, 0, 3 * Ed, 0);
      attn_fused<<<NBA * NHEAD, blk, 0, stream>>>(qkvbuf, ah, al);
    }
    // Wo: 64-tile counted-vmcnt pipeline + split-K=2 (2400 blocks)
    GEMM3(64, 0, 1, E_BIAS | E_SPLK, 2, NF, Ahp, Alp, woH, woL, bo_l, NF, hbuf, NU, NU,
          Mf, Ed, Ed, Ed, 0, 0, 0, Ed, 0);

    wcvt_t_split<<<dim3((4 * Ed) / 32, Ed / 32), wblk, 0, stream>>>(Wf1_l, f1H, f1L, Ed, 4 * Ed);
    wcvt_t_split<<<dim3(Ed / 32, (4 * Ed) / 32), wblk, 0, stream>>>(Wf2_l, f2H, f2L, 4 * Ed, Ed);

    ln_split<<<Mf, blk, 0, stream>>>(hbuf, ln2_g + (size_t)l * Ed, ln2_b + (size_t)l * Ed, Ahp, Alp);

    for (int row0 = 0; row0 < Mf; row0 += 2048) {
      int rows = (Mf - row0 < 2048) ? (Mf - row0) : 2048;
      GEMM3(64, 0, 1, E_BIAS | E_GELU | E_OUTS, 1, NF,
            Ahp + (size_t)row0 * Ed, Alp + (size_t)row0 * Ed, f1H, f1L, bf1_l, NF,
            (float*)nullptr, Ch2, Cl2, rows, 4 * Ed, Ed, Ed, 0, 0, 0, 4 * Ed, 0);
      // split-K=4: K=3072 -> 4x768, fp32 atomic accumulate onto residual in hbuf
      GEMM3(64, 0, 1, E_BIAS | E_SPLK, 4, NF, Ch2, Cl2, f2H, f2L, bf2_l, NF,
            hbuf + (size_t)row0 * Ed, NU, NU, rows, Ed, 4 * Ed, 4 * Ed, 0, 0, 0, Ed, 0);
    }
  }

  // ---------------- tail ----------------
  ushortT* ssH = (ushortT*)pool; ushortT* ssL = ssH + 1769472;
  wcvt_split_tm<<<512, blk, 0, stream>>>(ssm_w, ssH, ssL, Ed, Ed, 3);
  float* S = (float*)Ahp;   // h + s (plane area)
  GEMM3(128, 2, 0, E_BIAS | E_RES, 1, hbuf, NUS, NUS, ssH, ssL, ssm_b, hbuf, S, NU, NU,
        Mf, Ed, Ed * 3, Ed, Ff, 1, Ed, Ed, 0);

  float* L = pool;          // final LN out (overwrites ssH, dead)
  ln_f32<<<Mf, blk, 0, stream>>>(S, ssm_g, ssm_bn, L);
  float* mout = (float*)Ahp;
  mean_kernel<<<Bsz, blk, 0, stream>>>(L, mout);
  gemm_cls<<<dim3(2, Bsz / BM), blk, 0, stream>>>(
      mout, W_out, b_out, out, Bsz, NCls, Ed, Ed, NCls);
}

// Round 8
// 5478.110 us; speedup vs baseline: 1.0217x; 1.0217x over previous
//
#include <hip/hip_runtime.h>
#include <hip/hip_bf16.h>
#include <math.h>

// ---------------- problem constants ----------------
#define Bsz 512
#define Tin 96
#define DIN 64
#define Hd  256
#define Pp  2
#define Ll  4
#define NHEAD 8
#define Ed  768          // 3*H
#define NCls 100
#define Tp  48           // T/P tokens after patch
#define Ff  25           // rfft freqs of 48
#define F2  13           // rfft freqs of 25
#define DH  96           // E / HEADS

// epilogue flags
#define E_BIAS 1
#define E_PE   2
#define E_RES  4
#define E_ACC  8
#define E_GELU 16
#define E_OUTS 32        // write split hi/lo bf16 planes
#define E_SPLK 64        // split-K: atomicAdd partials into C

typedef unsigned short ushortT;
typedef unsigned short ushort8 __attribute__((ext_vector_type(8)));
typedef short short8 __attribute__((ext_vector_type(8)));
typedef float f32x4 __attribute__((ext_vector_type(4)));

static __device__ __forceinline__ ushortT f2bf(float f) {
  __hip_bfloat16 h = __float2bfloat16(f);
  return *reinterpret_cast<ushortT*>(&h);
}
static __device__ __forceinline__ float bfbits2f(ushortT u) {
  unsigned int x = ((unsigned int)u) << 16;
  return __uint_as_float(x);
}
static __device__ __forceinline__ void split2(float v, ushortT& h, ushortT& l) {
  h = f2bf(v);
  l = f2bf(v - bfbits2f(h));
}

// async global->LDS, 16B per lane; LDS dest is wave-uniform base + lane*16,
// global src is per-lane (lets us pre-swizzle the source for a swizzled layout).
typedef const __attribute__((address_space(1))) void* gas1_t;
typedef __attribute__((address_space(3))) void* las3_t;
static __device__ __forceinline__ void gload16(const void* g, void* l) {
  __builtin_amdgcn_global_load_lds((gas1_t)g, (las3_t)l, 16, 0, 0);
}

// =================== bf16x3 split MFMA GEMM ===================
// AMODE: 0 plain; 1 diff along Tdim; 2 tap-major conv (K=(tap,i), Kin inner)
// ASRC:  0 A fp32 [M,K]; 1 A pre-split planes Ah/Al [M,K] bf16
// BMS:   M-tile select. 128 -> 128x128 tile, wave tile 64x64 (48 FLOP/LDS-B,
//        32KB LDS) for M>=12800 GEMMs; 64 -> 64x128, wave tile 32x64
//        (33 FLOP/B, 24KB LDS) for grid-starved small-M GEMMs.
// R6-proven configuration (best measured wall 5457us). R7's counted-vmcnt
// double-buffer was null-to-negative (T4 needs the 8-phase interleave;
// on a 2-barrier structure it only adds LDS pressure) — reverted.
// K-loop: single-buffer gload_lds + __syncthreads + setprio (R1-proven;
// >32KB LDS collapses residency, R2/R3 measured).
// XOR swizzle byte^(((row>>1)&3)<<4): pre-swizzled global source, linear
// LDS dest, swizzled ds_read (conflict-free, measured 0 since R1).
constexpr int GBN = 128, GBK = 32;

template<int BMS, int AMODE, int ASRC, int EPI>
__global__ __launch_bounds__(256) void gemm3(
    const float* __restrict__ A,
    const ushortT* __restrict__ Ah, const ushortT* __restrict__ Al,
    const ushortT* __restrict__ Bh, const ushortT* __restrict__ Bl,
    const float* __restrict__ bias, const float* __restrict__ extra,
    float* __restrict__ C, ushortT* __restrict__ Coh, ushortT* __restrict__ Col,
    int M, int N, int K, int Ald, int Tdim, int lo, int Kin, int Cld, int coff,
    int Mt, int Nt, int mmaj, int ksn)
{
  constexpr int GBMv = BMS;            // 128 or 64
  constexpr int WMF  = GBMv / 32;      // M-frags per wave: 4 or 2
  constexpr int ARPW = GBMv / 4;       // A rows staged per wave: 32 or 16
  constexpr int TPR  = 256 / GBMv;     // threads per A-row (ASRC0): 2 or 4
  constexpr int EPT  = 32 / TPR;       // shorts per thread (ASRC0): 16 or 8

  __shared__ __align__(16) ushortT Ash[GBMv * GBK];
  __shared__ __align__(16) ushortT Asl[GBMv * GBK];
  __shared__ __align__(16) ushortT Bsh[GBN * GBK];
  __shared__ __align__(16) ushortT Bsl[GBN * GBK];
  int tid = threadIdx.x;

  // ---- bijective XCD-aware swizzle over [0, G) ----
  int lin = blockIdx.x;
  int G = gridDim.x;
  int r8 = lin & 7, s8 = lin >> 3;
  int q = G >> 3, rem = G & 7;
  int start = r8 * q + (r8 < rem ? r8 : rem);
  int idx = start + s8;
  int tiles = Mt * Nt;
  int ks = 0;
  if (ksn > 1) { ks = idx / tiles; idx -= ks * tiles; }
  int mt, nt;
  if (mmaj) { mt = idx / Nt; nt = idx - mt * Nt; }
  else      { nt = idx / Mt; mt = idx - nt * Mt; }
  int m0 = mt * GBMv, n0 = nt * GBN;
  int kper = K / ksn;
  int kbeg = ks * kper, kend = kbeg + kper;

  int wid = tid >> 6, lane = tid & 63;
  int wm = wid & 1, wn = wid >> 1;       // 2 M-waves x 2 N-waves
  int m16 = lane & 15, quad = lane >> 4;

  f32x4 acc[WMF][4] = {};

  // ---- gload staging geometry ----
  int gcb = (lane & 3) << 4;                       // byte col within 64B row
  // B: 128 rows = 4 waves x 32 rows, 2 calls of 16 rows each per plane
  int growB = (wid << 5) + (lane >> 2);
  int scbB  = gcb ^ (((growB >> 1) & 3) << 4);     // swz(row+16)==swz(row)
  char* ldsB = (char*)Bsh + (wid << 11);
  char* ldsb = (char*)Bsl + (wid << 11);
  size_t bo0 = ((size_t)(n0 + growB) * K) * 2 + scbB;
  size_t bo1 = bo0 + (size_t)16 * K * 2;
  // A: GBMv rows = 4 waves x ARPW rows (1 or 2 calls per plane)
  int growA = wid * ARPW + (lane >> 2);
  int scbA  = gcb ^ (((growA >> 1) & 3) << 4);
  char* ldsA = (char*)Ash + wid * ARPW * 64;
  char* ldsa = (char*)Asl + wid * ARPW * 64;
  size_t ao0 = 0, ao1 = 0;
  if (ASRC == 1) {
    int ar0 = m0 + growA;  if (ar0 >= M) ar0 = M - 1;
    ao0 = ((size_t)ar0 * Ald) * 2 + scbA;
    if (ARPW == 32) {
      int ar1 = m0 + growA + 16;  if (ar1 >= M) ar1 = M - 1;
      ao1 = ((size_t)ar1 * Ald) * 2 + scbA;
    }
  }

  // ---- ASRC=0 compute-staging store addresses (swizzled, short-index) ----
  int srow = tid / TPR;                // 0..GBMv-1
  int sseg = (tid % TPR) * EPT;        // short offset within the 32-K row
  int sswz = ((srow >> 1) & 3) << 3;   // swizzle in short units (16B granule)

  // ---- fragment read addressing (same XOR) ----
  int fswz = ((m16 >> 1) & 3) << 3;
  int scf  = (quad << 3) ^ fswz;

  for (int k0 = kbeg; k0 < kend; k0 += GBK) {
    size_t kb = (size_t)k0 * 2;
    // ---- stage B (always planes, DMA direct to LDS) ----
    gload16((const char*)Bh + bo0 + kb, ldsB);
    gload16((const char*)Bh + bo1 + kb, ldsB + 1024);
    gload16((const char*)Bl + bo0 + kb, ldsb);
    gload16((const char*)Bl + bo1 + kb, ldsb + 1024);
    // ---- stage A ----
    if (ASRC == 1) {
      gload16((const char*)Ah + ao0 + kb, ldsA);
      gload16((const char*)Al + ao0 + kb, ldsa);
      if (ARPW == 32) {
        gload16((const char*)Ah + ao1 + kb, ldsA + 1024);
        gload16((const char*)Al + ao1 + kb, ldsa + 1024);
      }
    } else {
      int row = m0 + srow;
      if (row >= M) row = M - 1;
      float tf[EPT];
      if (AMODE == 0) {
        const float* p = A + (size_t)row * Ald + k0 + sseg;
#pragma unroll
        for (int j = 0; j < EPT; j += 4) {
          float4 v = *(const float4*)(p + j);
          tf[j] = v.x; tf[j+1] = v.y; tf[j+2] = v.z; tf[j+3] = v.w;
        }
      } else if (AMODE == 1) {
        int t = row % Tdim;
        const float* p = A + (size_t)row * Ald + k0 + sseg;
#pragma unroll
        for (int j = 0; j < EPT; j += 4) {
          float4 v = *(const float4*)(p + j);
          float4 w = (t != 0) ? *(const float4*)(p - Ald + j) : v;
          tf[j] = v.x - w.x; tf[j+1] = v.y - w.y;
          tf[j+2] = v.z - w.z; tf[j+3] = v.w - w.w;
        }
      } else {   // tap-major conv; tap uniform over this EPT-seg (Kin%EPT==0)
        int kk = k0 + sseg;
        int tap = kk / Kin;
        int i0  = kk - tap * Kin;
        int bb = row / Tdim;
        int t  = row - bb * Tdim;
        int tt = t - lo + tap;
        if (tt >= 0 && tt < Tdim) {
          const float* p = A + ((size_t)bb * Tdim + tt) * Ald + i0;
#pragma unroll
          for (int j = 0; j < EPT; j += 4) {
            float4 v = *(const float4*)(p + j);
            tf[j] = v.x; tf[j+1] = v.y; tf[j+2] = v.z; tf[j+3] = v.w;
          }
        } else {
#pragma unroll
          for (int j = 0; j < EPT; j++) tf[j] = 0.0f;
        }
      }
      ushortT th[EPT], tl[EPT];
#pragma unroll
      for (int j = 0; j < EPT; j++) split2(tf[j], th[j], tl[j]);
#pragma unroll
      for (int c8 = 0; c8 < EPT / 8; c8++) {
        int st = srow * GBK + ((sseg + c8 * 8) ^ sswz);
        *(ushort8*)&Ash[st] = *(ushort8*)&th[c8 * 8];
        *(ushort8*)&Asl[st] = *(ushort8*)&tl[c8 * 8];
      }
    }
    __syncthreads();
    short8 ah[WMF], al[WMF], bh[4], bl[4];
#pragma unroll
    for (int i = 0; i < WMF; i++) {
      int ro = (wm * (WMF * 16) + i * 16 + m16) * GBK + scf;
      ah[i] = *(short8*)&Ash[ro];
      al[i] = *(short8*)&Asl[ro];
    }
#pragma unroll
    for (int j = 0; j < 4; j++) {
      int ro = (wn * 64 + j * 16 + m16) * GBK + scf;
      bh[j] = *(short8*)&Bsh[ro];
      bl[j] = *(short8*)&Bsl[ro];
    }
    __builtin_amdgcn_s_setprio(1);
#pragma unroll
    for (int i = 0; i < WMF; i++)
#pragma unroll
      for (int j = 0; j < 4; j++) {
        acc[i][j] = __builtin_amdgcn_mfma_f32_16x16x32_bf16(ah[i], bh[j], acc[i][j], 0, 0, 0);
        acc[i][j] = __builtin_amdgcn_mfma_f32_16x16x32_bf16(al[i], bh[j], acc[i][j], 0, 0, 0);
        acc[i][j] = __builtin_amdgcn_mfma_f32_16x16x32_bf16(ah[i], bl[j], acc[i][j], 0, 0, 0);
      }
    __builtin_amdgcn_s_setprio(0);
    __syncthreads();
  }

  // ---- epilogue: C/D map col=lane&15, row=quad*4+r ----
#pragma unroll
  for (int i = 0; i < WMF; i++) {
#pragma unroll
    for (int j = 0; j < 4; j++) {
      int colg = n0 + wn * 64 + j * 16 + m16;
#pragma unroll
      for (int rr = 0; rr < 4; rr++) {
        int rowg = m0 + wm * (WMF * 16) + i * 16 + quad * 4 + rr;
        if (rowg >= M) continue;
        float v = acc[i][j][rr];
        if ((EPI & E_BIAS) && ks == 0) v += bias[colg];
        if (EPI & E_PE)   v += extra[(size_t)(rowg % Tdim) * N + colg];
        if (EPI & E_RES)  v += extra[(size_t)rowg * Cld + colg];
        if (EPI & E_GELU) v = 0.5f * v * (1.0f + erff(v * 0.70710678118654752f));
        size_t off = (size_t)rowg * Cld + coff + colg;
        if (EPI & E_SPLK) {
          atomicAdd(&C[off], v);
        } else if (EPI & E_OUTS) {
          ushortT h, l; split2(v, h, l);
          Coh[off] = h; Col[off] = l;
        } else {
          if (EPI & E_ACC) v += C[off];
          C[off] = v;
        }
      }
    }
  }
}

#define GEMM3(BMS_, AM, AS, EP, KS, Asrc, AhP, AlP, BhP, BlP, biasP, extraP, CP, CohP, ColP, \
              Mv, Nv, Kv, AldV, TdimV, loV, KinV, CldV, coffV) \
  do { int Mt_ = ((Mv) + (BMS_) - 1) / (BMS_), Nt_ = (Nv) / GBN; \
       int mm_ = ((Mv) >= (Nv)) ? 1 : 0; \
       gemm3<BMS_, AM, AS, EP><<<dim3(Mt_ * Nt_ * (KS)), dim3(256), 0, stream>>>( \
           Asrc, AhP, AlP, BhP, BlP, biasP, extraP, CP, CohP, ColP, \
           Mv, Nv, Kv, AldV, TdimV, loV, KinV, CldV, coffV, Mt_, Nt_, mm_, KS); } while (0)

// ====== weight transpose + split: fp32 [K][N] -> bf16 hi/lo [N][K] ======
__global__ __launch_bounds__(256) void wcvt_t_split(
    const float* __restrict__ W, ushortT* __restrict__ Wh, ushortT* __restrict__ Wl,
    int K, int N)
{
  __shared__ float t[32][33];
  int k0 = blockIdx.y * 32, n0 = blockIdx.x * 32;
  int tx = threadIdx.x;
  int ty = threadIdx.y;
#pragma unroll
  for (int dy = 0; dy < 32; dy += 8)
    t[ty + dy][tx] = W[(size_t)(k0 + ty + dy) * N + n0 + tx];
  __syncthreads();
#pragma unroll
  for (int dy = 0; dy < 32; dy += 8) {
    float v = t[tx][ty + dy];
    ushortT h, l;
    split2(v, h, l);
    size_t off = (size_t)(n0 + ty + dy) * K + k0 + tx;
    Wh[off] = h; Wl[off] = l;
  }
}

// ====== flat split: fp32 -> bf16 hi/lo ======
__global__ __launch_bounds__(256) void wcvt_split(
    const float* __restrict__ W, ushortT* __restrict__ Wh, ushortT* __restrict__ Wl, int n)
{
  int gid = blockIdx.x * 256 + threadIdx.x;
  int stride = gridDim.x * 256;
  for (int i = gid; i < n; i += stride) {
    ushortT h, l;
    split2(W[i], h, l);
    Wh[i] = h; Wl[i] = l;
  }
}

// ====== conv weight split, tap-major: [O][Kin][NT] -> [O][NT*Kin] ======
__global__ __launch_bounds__(256) void wcvt_split_tm(
    const float* __restrict__ W, ushortT* __restrict__ Wh, ushortT* __restrict__ Wl,
    int O, int Kin, int NT)
{
  int n = O * Kin * NT;
  int gid = blockIdx.x * 256 + threadIdx.x;
  int stride = gridDim.x * 256;
  for (int idx = gid; idx < n; idx += stride) {
    int o = idx / (Kin * NT);
    int rr = idx - o * (Kin * NT);
    int tap = rr / Kin;
    int i = rr - tap * Kin;
    float v = W[(size_t)o * Kin * NT + (size_t)i * NT + tap];
    ushortT h, l;
    split2(v, h, l);
    Wh[idx] = h; Wl[idx] = l;
  }
}

// =================== fp32 fallback GEMM (classifier only) ===================
constexpr int BM = 64, BN = 64, BK = 16, TM = 4, TN = 4;
__global__ __launch_bounds__(256) void gemm_cls(
    const float* __restrict__ A, const float* __restrict__ Bw,
    const float* __restrict__ bias, float* __restrict__ C,
    int M, int N, int K, int Ald, int Cld)
{
  __shared__ alignas(16) float As[BK][BM + 4];
  __shared__ alignas(16) float Bs[BK][BN + 4];
  int tid = threadIdx.x;
  int n0 = blockIdx.x * BN;
  int m0 = blockIdx.y * BM;
  int tx = tid & 15, ty = tid >> 4;
  float acc[TM][TN];
#pragma unroll
  for (int i = 0; i < TM; i++)
#pragma unroll
    for (int j = 0; j < TN; j++) acc[i][j] = 0.0f;
  int a_m = tid >> 2, a_k = (tid & 3) * 4;
  int b_k = tid >> 4, b_n = (tid & 15) * 4;
  for (int k0 = 0; k0 < K; k0 += BK) {
    int row = m0 + a_m;
#pragma unroll
    for (int j = 0; j < 4; j++)
      As[a_k + j][a_m] = A[(size_t)row * Ald + k0 + a_k + j];
    int kk = k0 + b_k;
#pragma unroll
    for (int j = 0; j < 4; j++) {
      int nn = n0 + b_n + j;
      Bs[b_k][b_n + j] = (nn < N) ? Bw[(size_t)kk * N + nn] : 0.0f;
    }
    __syncthreads();
#pragma unroll
    for (int k = 0; k < BK; k++) {
      float4 av = *reinterpret_cast<const float4*>(&As[k][ty * TM]);
      float4 bv = *reinterpret_cast<const float4*>(&Bs[k][tx * TN]);
      float a4[4] = {av.x, av.y, av.z, av.w};
      float b4[4] = {bv.x, bv.y, bv.z, bv.w};
#pragma unroll
      for (int i = 0; i < TM; i++)
#pragma unroll
        for (int j = 0; j < TN; j++) acc[i][j] += a4[i] * b4[j];
    }
    __syncthreads();
  }
#pragma unroll
  for (int i = 0; i < TM; i++) {
    int row = m0 + ty * TM + i;
#pragma unroll
    for (int j = 0; j < TN; j++) {
      int col = n0 + tx * TN + j;
      if (col >= N) continue;
      C[(size_t)row * Cld + col] = acc[i][j] + bias[col];
    }
  }
}

// ---- rfft over 48 tokens, real part (fp32) ----
__global__ __launch_bounds__(256) void rfft48_kernel(
    const float* __restrict__ hp, float* __restrict__ f)
{
  int kf = blockIdx.x;
  int b  = blockIdx.y;
  int tid = threadIdx.x;
  __shared__ float ct[48];
  if (tid < 48) {
    int rr = (kf * tid) % 48;
    ct[tid] = cosf(6.2831853071795864f * (float)rr / 48.0f);
  }
  __syncthreads();
  const float* hb = hp + (size_t)b * Tp * Hd;
  float s = 0.0f;
  for (int t = 0; t < 48; t++) s += hb[t * Hd + tid] * ct[t];
  f[((size_t)b * Ff + kf) * Hd + tid] = s;
}

// ---- fused fourier attention: logits -> softmax -> circulant(G) @ v ----
__global__ __launch_bounds__(256) void attn_fused(
    const float* __restrict__ qkv,     // chunk [nb*25, 2304]
    ushortT* __restrict__ oh, ushortT* __restrict__ ol)
{
  int bh = blockIdx.x;
  int b = bh >> 3, h = bh & 7;
  __shared__ float qs[Ff * DH], ks[Ff * DH], vs[Ff * DH];
  __shared__ float ct[F2 * Ff], st[F2 * Ff];
  __shared__ float red[F2 * DH];
  __shared__ float sm[F2];
  __shared__ float G[Ff];
  int tid = threadIdx.x;
  const float* base = qkv + (size_t)b * Ff * (3 * Ed) + h * DH;
  for (int e = tid; e < Ff * DH; e += 256) {
    int t = e / DH, d = e - t * DH;
    size_t ro = (size_t)t * (3 * Ed) + d;
    qs[e] = base[ro];
    ks[e] = base[ro + Ed];
    vs[e] = base[ro + 2 * Ed];
  }
  for (int e = tid; e < F2 * Ff; e += 256) {
    int fq = e / Ff, t = e - fq * Ff;
    int rr = (fq * t) % Ff;
    float ang = 6.2831853071795864f * (float)rr / 25.0f;
    ct[e] = cosf(ang); st[e] = sinf(ang);
  }
  __syncthreads();
  for (int e = tid; e < F2 * DH; e += 256) {
    int fq = e / DH, d = e - fq * DH;
    float qr = 0, qi = 0, kr = 0, ki = 0;
    for (int t = 0; t < Ff; t++) {
      float c = ct[fq * Ff + t], s = st[fq * Ff + t];
      float qv = qs[t * DH + d], kv = ks[t * DH + d];
      qr += qv * c; qi += qv * s; kr += kv * c; ki += kv * s;
    }
    red[e] = qr * kr + qi * ki;
  }
  __syncthreads();
  if (tid < F2) {
    float s = 0;
    for (int d = 0; d < DH; d++) s += red[tid * DH + d];
    sm[tid] = s * 0.10206207261596575f;  // 96^-0.5
  }
  __syncthreads();
  if (tid == 0) {
    float mx = sm[0];
    for (int f = 1; f < F2; f++) mx = fmaxf(mx, sm[f]);
    float den = 0;
    for (int f = 0; f < F2; f++) { float e2 = expf(sm[f] - mx); sm[f] = e2; den += e2; }
    float inv = 1.0f / den;
    for (int f = 0; f < F2; f++)
      sm[f] *= inv * ((f == 0) ? (1.0f / 25.0f) : (2.0f / 25.0f));
  }
  __syncthreads();
  if (tid < Ff) {
    float g = 0;
    for (int f = 0; f < F2; f++) g += sm[f] * ct[f * Ff + tid];
    G[tid] = g;
  }
  __syncthreads();
  size_t ob = ((size_t)b * Ff) * Ed + h * DH;
  for (int e = tid; e < Ff * DH; e += 256) {
    int t = e / DH, d = e - t * DH;
    float o = 0;
    int dd = t;
    for (int tp = 0; tp < Ff; tp++) {
      o += G[dd] * vs[tp * DH + d];
      dd--; if (dd < 0) dd += Ff;
    }
    ushortT hh, ll;
    split2(o, hh, ll);
    size_t off = ob + (size_t)t * Ed + d;
    oh[off] = hh; ol[off] = ll;
  }
}

// ---- layernorm over 768: shuffle-reduce (2 barriers vs old 16) ----
// 256 thr = 4 waves; per-wave __shfl_xor reduce, 4-slot LDS combine.
static __device__ __forceinline__ float wave_sum(float s) {
#pragma unroll
  for (int o = 32; o > 0; o >>= 1) s += __shfl_xor(s, o);
  return s;
}

__global__ __launch_bounds__(256) void ln_split(
    const float* __restrict__ x, const float* __restrict__ g,
    const float* __restrict__ bb, ushortT* __restrict__ yh, ushortT* __restrict__ yl)
{
  int row = blockIdx.x;
  int tid = threadIdx.x;
  int wid = tid >> 6, lane = tid & 63;
  const float* xr = x + (size_t)row * Ed;
  float v0 = xr[tid], v1 = xr[tid + 256], v2 = xr[tid + 512];
  __shared__ float wsum[4], wsq[4];
  float s = wave_sum(v0 + v1 + v2);
  if (lane == 0) wsum[wid] = s;
  __syncthreads();
  float m = (wsum[0] + wsum[1] + wsum[2] + wsum[3]) * (1.0f / 768.0f);
  float d0 = v0 - m, d1 = v1 - m, d2 = v2 - m;
  float q = wave_sum(d0 * d0 + d1 * d1 + d2 * d2);
  if (lane == 0) wsq[wid] = q;
  __syncthreads();
  float inv = rsqrtf((wsq[0] + wsq[1] + wsq[2] + wsq[3]) * (1.0f / 768.0f) + 1e-5f);
  size_t basei = (size_t)row * Ed;
  float o0 = d0 * inv * g[tid] + bb[tid];
  float o1 = d1 * inv * g[tid + 256] + bb[tid + 256];
  float o2 = d2 * inv * g[tid + 512] + bb[tid + 512];
  ushortT h, l;
  split2(o0, h, l); yh[basei + tid] = h;       yl[basei + tid] = l;
  split2(o1, h, l); yh[basei + tid + 256] = h; yl[basei + tid + 256] = l;
  split2(o2, h, l); yh[basei + tid + 512] = h; yl[basei + tid + 512] = l;
}

// ---- layernorm over 768, fp32 out (final), shuffle-reduce ----
__global__ __launch_bounds__(256) void ln_f32(
    const float* __restrict__ x, const float* __restrict__ g,
    const float* __restrict__ bb, float* __restrict__ y)
{
  int row = blockIdx.x;
  int tid = threadIdx.x;
  int wid = tid >> 6, lane = tid & 63;
  const float* xr = x + (size_t)row * Ed;
  float v0 = xr[tid], v1 = xr[tid + 256], v2 = xr[tid + 512];
  __shared__ float wsum[4], wsq[4];
  float s = wave_sum(v0 + v1 + v2);
  if (lane == 0) wsum[wid] = s;
  __syncthreads();
  float m = (wsum[0] + wsum[1] + wsum[2] + wsum[3]) * (1.0f / 768.0f);
  float d0 = v0 - m, d1 = v1 - m, d2 = v2 - m;
  float q = wave_sum(d0 * d0 + d1 * d1 + d2 * d2);
  if (lane == 0) wsq[wid] = q;
  __syncthreads();
  float inv = rsqrtf((wsq[0] + wsq[1] + wsq[2] + wsq[3]) * (1.0f / 768.0f) + 1e-5f);
  float* yr = y + (size_t)row * Ed;
  yr[tid]       = d0 * inv * g[tid]       + bb[tid];
  yr[tid + 256] = d1 * inv * g[tid + 256] + bb[tid + 256];
  yr[tid + 512] = d2 * inv * g[tid + 512] + bb[tid + 512];
}

// ---- mean over 25 tokens ----
__global__ __launch_bounds__(256) void mean_kernel(
    const float* __restrict__ x, float* __restrict__ y)
{
  int b = blockIdx.x;
  int tid = threadIdx.x;
  for (int c = tid; c < Ed; c += 256) {
    float s = 0;
    for (int t = 0; t < Ff; t++) s += x[((size_t)b * Ff + t) * Ed + c];
    y[(size_t)b * Ed + c] = s * (1.0f / 25.0f);
  }
}

extern "C" void kernel_launch(void* const* d_in, const int* in_sizes, int n_in,
                              void* d_out, int out_size, void* d_ws, size_t ws_size,
                              hipStream_t stream)
{
  const float* x       = (const float*)d_in[0];
  const float* W_in    = (const float*)d_in[1];
  const float* b_in    = (const float*)d_in[2];
  const float* pe      = (const float*)d_in[3];
  const float* W_shape = (const float*)d_in[4];
  const float* b_shape = (const float*)d_in[5];
  const float* W_patch = (const float*)d_in[6];
  const float* b_patch = (const float*)d_in[7];
  const float* conv_w1 = (const float*)d_in[8];
  const float* conv_b1 = (const float*)d_in[9];
  const float* conv_w2 = (const float*)d_in[10];
  const float* conv_b2 = (const float*)d_in[11];
  const float* conv_w4 = (const float*)d_in[12];
  const float* conv_b4 = (const float*)d_in[13];
  const float* ln1_g   = (const float*)d_in[14];
  const float* ln1_b   = (const float*)d_in[15];
  const float* Wqkv    = (const float*)d_in[16];
  const float* Wo      = (const float*)d_in[17];
  const float* bo      = (const float*)d_in[18];
  const float* ln2_g   = (const float*)d_in[19];
  const float* ln2_b   = (const float*)d_in[20];
  const float* Wf1     = (const float*)d_in[21];
  const float* bf1     = (const float*)d_in[22];
  const float* Wf2     = (const float*)d_in[23];
  const float* bf2     = (const float*)d_in[24];
  const float* ssm_w   = (const float*)d_in[25];
  const float* ssm_b   = (const float*)d_in[26];
  const float* ssm_g   = (const float*)d_in[27];
  const float* ssm_bn  = (const float*)d_in[28];
  const float* W_out   = (const float*)d_in[29];
  const float* b_out   = (const float*)d_in[30];
  float* out = (float*)d_out;

  // ---- workspace: h 39.3MB | planes 39.3MB | pool 44.0MB = 122.7MB ----
  float* hbuf = (float*)d_ws;                    // 9,830,400 fl
  ushortT* Ahp = (ushortT*)(hbuf + 9830400);     // 9,830,400 slots
  ushortT* Alp = Ahp + 9830400;                  // 9,830,400 slots
  float* pool = (float*)(Alp + 9830400);         // 11,010,048 fl

  dim3 blk(256);
  dim3 wblk(32, 8);
  const int Mf = Bsz * Ff;   // 12800
  const ushortT* NUS = nullptr;
  const float* NF = nullptr;
  ushortT* NU = nullptr;

  // ---------------- phase-0 weights (pool + 6,291,456 fl) ----------------
  ushortT* p0w = (ushortT*)(pool + 6291456);
  ushortT* WinH = p0w + 0;        ushortT* WinL = p0w + 16384;
  ushortT* WshH = p0w + 32768;    ushortT* WshL = p0w + 98304;
  ushortT* WpaH = p0w + 163840;   ushortT* WpaL = p0w + 294912;
  ushortT* c1H  = p0w + 425984;   ushortT* c1L  = p0w + 491520;
  ushortT* c2H  = p0w + 557056;   ushortT* c2L  = p0w + 688128;
  ushortT* c4H  = p0w + 819200;   ushortT* c4L  = p0w + 1081344;
  wcvt_t_split<<<dim3(Hd / 32, DIN / 32), wblk, 0, stream>>>(W_in, WinH, WinL, DIN, Hd);
  wcvt_t_split<<<dim3(Hd / 32, Hd / 32), wblk, 0, stream>>>(W_shape, WshH, WshL, Hd, Hd);
  wcvt_t_split<<<dim3(Hd / 32, (Pp * Hd) / 32), wblk, 0, stream>>>(W_patch, WpaH, WpaL, Pp * Hd, Hd);
  wcvt_split<<<64, blk, 0, stream>>>(conv_w1, c1H, c1L, Hd * Hd);
  wcvt_split_tm<<<128, blk, 0, stream>>>(conv_w2, c2H, c2L, Hd, Hd, 2);
  wcvt_split_tm<<<256, blk, 0, stream>>>(conv_w4, c4H, c4L, Hd, Hd, 4);

  // ---------------- phase 0: 2 chunks of 256 batches ----------------
  float* s0  = (float*)Ahp;
  float* s1f = (float*)Ahp + 6291456;
  float* s1  = pool;
  for (int c = 0; c < 2; c++) {
    const int NB = 256;
    const int M96 = NB * Tin;      // 24576
    const int Mpch = NB * Tp;      // 12288
    const float* xc = x + (size_t)c * NB * Tin * DIN;

    GEMM3(64, 0, 0, E_BIAS | E_PE, 1, xc, NUS, NUS, WinH, WinL, b_in, pe, s0, NU, NU,
          M96, Hd, DIN, DIN, Tin, 0, 0, Hd, 0);
    GEMM3(64, 1, 0, E_BIAS | E_RES, 1, s0, NUS, NUS, WshH, WshL, b_shape, s0, s1, NU, NU,
          M96, Hd, Hd, Hd, Tin, 0, 0, Hd, 0);
    GEMM3(64, 0, 0, E_BIAS, 1, s1, NUS, NUS, WpaH, WpaL, b_patch, NF, s0, NU, NU,
          Mpch, Hd, Pp * Hd, Pp * Hd, 0, 0, 0, Hd, 0);
    rfft48_kernel<<<dim3(Ff, NB), blk, 0, stream>>>(s0, s1f + (size_t)c * NB * Ff * Hd);
  }
  // conv GEMMs over all 12800 rows at once
  GEMM3(64, 0, 0, E_BIAS, 1, s1f, NUS, NUS, c1H, c1L, conv_b1, NF, hbuf, NU, NU,
        Mf, Hd, Hd, Hd, Ff, 0, 0, Ed, 0);
  GEMM3(64, 2, 0, E_BIAS, 1, s1f, NUS, NUS, c2H, c2L, conv_b2, NF, hbuf, NU, NU,
        Mf, Hd, Hd * 2, Hd, Ff, 0, Hd, Ed, Hd);
  GEMM3(64, 2, 0, E_BIAS, 1, s1f, NUS, NUS, c4H, c4L, conv_b4, NF, hbuf, NU, NU,
        Mf, Hd, Hd * 4, Hd, Ff, 1, Hd, Ed, 2 * Hd);

  // ---------------- transformer layers ----------------
  float* qkvbuf = pool;                          // 7,372,800 fl (chunk 3200x2304)
  ushortT* lwA = (ushortT*)(pool + 7372800);
  ushortT* qkH = lwA + 0;        ushortT* qkL = lwA + 1769472;
  ushortT* woH = lwA + 3538944;  ushortT* woL = lwA + 4128768;
  ushortT* Ch2 = (ushortT*)pool;                 // ffmid hi (2048x3072)
  ushortT* Cl2 = Ch2 + 6291456;                  // ffmid lo
  ushortT* lwB = (ushortT*)(pool + 6291456);
  ushortT* f1H = lwB + 0;        ushortT* f1L = lwB + 2359296;
  ushortT* f2H = lwB + 4718592;  ushortT* f2L = lwB + 7077888;

  const int NBA = 128;           // batches per attention chunk (4 chunks)
  const int Mca = NBA * Ff;      // 3200 rows

  for (int l = 0; l < Ll; l++) {
    const float* Wqkv_l = Wqkv + (size_t)l * Ed * (3 * Ed);
    const float* Wo_l   = Wo   + (size_t)l * Ed * Ed;
    const float* bo_l   = bo   + (size_t)l * Ed;
    const float* Wf1_l  = Wf1  + (size_t)l * Ed * (4 * Ed);
    const float* bf1_l  = bf1  + (size_t)l * (4 * Ed);
    const float* Wf2_l  = Wf2  + (size_t)l * (4 * Ed) * Ed;
    const float* bf2_l  = bf2  + (size_t)l * Ed;

    wcvt_t_split<<<dim3((3 * Ed) / 32, Ed / 32), wblk, 0, stream>>>(Wqkv_l, qkH, qkL, Ed, 3 * Ed);
    wcvt_t_split<<<dim3(Ed / 32, Ed / 32), wblk, 0, stream>>>(Wo_l, woH, woL, Ed, Ed);

    ln_split<<<Mf, blk, 0, stream>>>(hbuf, ln1_g + (size_t)l * Ed, ln1_b + (size_t)l * Ed, Ahp, Alp);

    for (int c = 0; c < 4; c++) {
      ushortT* ah = Ahp + (size_t)c * Mca * Ed;
      ushortT* al = Alp + (size_t)c * Mca * Ed;
      GEMM3(64, 0, 1, 0, 1, NF, ah, al, qkH, qkL, NF, NF, qkvbuf, NU, NU,
            Mca, 3 * Ed, Ed, Ed, 0, 0, 0, 3 * Ed, 0);
      attn_fused<<<NBA * NHEAD, blk, 0, stream>>>(qkvbuf, ah, al);
    }
    // Wo: 128-tile (48 FLOP/LDS-B) + split-K=2, atomicAdd onto residual hbuf
    GEMM3(128, 0, 1, E_BIAS | E_SPLK, 2, NF, Ahp, Alp, woH, woL, bo_l, NF, hbuf, NU, NU,
          Mf, Ed, Ed, Ed, 0, 0, 0, Ed, 0);

    wcvt_t_split<<<dim3((4 * Ed) / 32, Ed / 32), wblk, 0, stream>>>(Wf1_l, f1H, f1L, Ed, 4 * Ed);
    wcvt_t_split<<<dim3(Ed / 32, (4 * Ed) / 32), wblk, 0, stream>>>(Wf2_l, f2H, f2L, 4 * Ed, Ed);

    ln_split<<<Mf, blk, 0, stream>>>(hbuf, ln2_g + (size_t)l * Ed, ln2_b + (size_t)l * Ed, Ahp, Alp);

    for (int row0 = 0; row0 < Mf; row0 += 2048) {
      int rows = (Mf - row0 < 2048) ? (Mf - row0) : 2048;
      GEMM3(64, 0, 1, E_BIAS | E_GELU | E_OUTS, 1, NF,
            Ahp + (size_t)row0 * Ed, Alp + (size_t)row0 * Ed, f1H, f1L, bf1_l, NF,
            (float*)nullptr, Ch2, Cl2, rows, 4 * Ed, Ed, Ed, 0, 0, 0, 4 * Ed, 0);
      // split-K=4: K=3072 -> 4x768, fp32 atomic accumulate onto residual in hbuf
      GEMM3(64, 0, 1, E_BIAS | E_SPLK, 4, NF, Ch2, Cl2, f2H, f2L, bf2_l, NF,
            hbuf + (size_t)row0 * Ed, NU, NU, rows, Ed, 4 * Ed, 4 * Ed, 0, 0, 0, Ed, 0);
    }
  }

  // ---------------- tail ----------------
  ushortT* ssH = (ushortT*)pool; ushortT* ssL = ssH + 1769472;
  wcvt_split_tm<<<512, blk, 0, stream>>>(ssm_w, ssH, ssL, Ed, Ed, 3);
  float* S = (float*)Ahp;   // h + s (plane area)
  GEMM3(128, 2, 0, E_BIAS | E_RES, 1, hbuf, NUS, NUS, ssH, ssL, ssm_b, hbuf, S, NU, NU,
        Mf, Ed, Ed * 3, Ed, Ff, 1, Ed, Ed, 0);

  float* L = pool;          // final LN out (overwrites ssH, dead)
  ln_f32<<<Mf, blk, 0, stream>>>(S, ssm_g, ssm_bn, L);
  float* mout = (float*)Ahp;
  mean_kernel<<<Bsz, blk, 0, stream>>>(L, mout);
  gemm_cls<<<dim3(2, Bsz / BM), blk, 0, stream>>>(
      mout, W_out, b_out, out, Bsz, NCls, Ed, Ed, NCls);
}

// Round 9
// 5075.534 us; speedup vs baseline: 1.1027x; 1.0793x over previous
//
#include <hip/hip_runtime.h>
#include <hip/hip_bf16.h>
#include <math.h>

// ---------------- problem constants ----------------
#define Bsz 512
#define Tin 96
#define DIN 64
#define Hd  256
#define Pp  2
#define Ll  4
#define NHEAD 8
#define Ed  768          // 3*H
#define NCls 100
#define Tp  48           // T/P tokens after patch
#define Ff  25           // rfft freqs of 48
#define F2  13           // rfft freqs of 25
#define DH  96           // E / HEADS

// epilogue flags
#define E_BIAS 1
#define E_PE   2
#define E_RES  4
#define E_ACC  8
#define E_GELU 16
#define E_OUTS 32        // write split hi/lo bf16 planes
#define E_SPLK 64        // split-K: atomicAdd partials into C

typedef unsigned short ushortT;
typedef unsigned short ushort8 __attribute__((ext_vector_type(8)));
typedef short short8 __attribute__((ext_vector_type(8)));
typedef float f32x4 __attribute__((ext_vector_type(4)));

static __device__ __forceinline__ ushortT f2bf(float f) {
  __hip_bfloat16 h = __float2bfloat16(f);
  return *reinterpret_cast<ushortT*>(&h);
}
static __device__ __forceinline__ float bfbits2f(ushortT u) {
  unsigned int x = ((unsigned int)u) << 16;
  return __uint_as_float(x);
}
static __device__ __forceinline__ void split2(float v, ushortT& h, ushortT& l) {
  h = f2bf(v);
  l = f2bf(v - bfbits2f(h));
}

// async global->LDS, 16B per lane; LDS dest is wave-uniform base + lane*16,
// global src is per-lane (lets us pre-swizzle the source for a swizzled layout).
typedef const __attribute__((address_space(1))) void* gas1_t;
typedef __attribute__((address_space(3))) void* las3_t;
static __device__ __forceinline__ void gload16(const void* g, void* l) {
  __builtin_amdgcn_global_load_lds((gas1_t)g, (las3_t)l, 16, 0, 0);
}

// =================== bf16x3 split MFMA GEMM ===================
// AMODE: 0 plain; 1 diff along Tdim; 2 tap-major conv (K=(tap,i), Kin inner)
// ASRC:  0 A fp32 [M,K]; 1 A pre-split planes Ah/Al [M,K] bf16
// GBKT=32 path (ASRC=0): R6-proven. BMS 128 -> 128x128 tile (48 FLOP/LDS-B,
//   32KB); BMS 64 -> 64x128 (24KB). Single-buffer gload/compute staging +
//   __syncthreads + setprio. Swizzle byte^(((row>>1)&3)<<4) on 64B rows.
// GBKT=64 path (ASRC=1, R9): 64x64x64 tile, exactly 32KB LDS (the measured
//   residency cap). Same 48 FLOP/LDS-B as 128^2, but HALF the vmcnt(0)
//   drains per element — R1-R8 showed every big GEMM pinned at
//   time = bytes/870GB/s regardless of tile/occupancy: drain-frequency-
//   limited memory-level parallelism. 24 MFMA per barrier pair.
//   Swizzle for 128B rows: byte ^ ((row&7)<<4) -> 2-way on ds_read_b128
//   (free, m136); source pre-swizzle ((lane&7)^(lane>>3))<<4.
constexpr int GBK = 32;

template<int BMS, int GBKT, int AMODE, int ASRC, int EPI>
__global__ __launch_bounds__(256) void gemm3(
    const float* __restrict__ A,
    const ushortT* __restrict__ Ah, const ushortT* __restrict__ Al,
    const ushortT* __restrict__ Bh, const ushortT* __restrict__ Bl,
    const float* __restrict__ bias, const float* __restrict__ extra,
    float* __restrict__ C, ushortT* __restrict__ Coh, ushortT* __restrict__ Col,
    int M, int N, int K, int Ald, int Tdim, int lo, int Kin, int Cld, int coff,
    int Mt, int Nt, int mmaj, int ksn)
{
  constexpr int GBMv = BMS;                        // M tile
  constexpr int GBNv = (GBKT == 64) ? 64 : 128;    // N tile
  constexpr int WMF  = GBMv / 32;                  // M-frags per wave (GBK32)
  constexpr int ARPW = GBMv / 4;
  constexpr int TPR  = 256 / GBMv;
  constexpr int EPT  = 32 / TPR;

  __shared__ __align__(16) ushortT Ash[GBMv * GBKT];
  __shared__ __align__(16) ushortT Asl[GBMv * GBKT];
  __shared__ __align__(16) ushortT Bsh[GBNv * GBKT];
  __shared__ __align__(16) ushortT Bsl[GBNv * GBKT];
  int tid = threadIdx.x;

  // ---- bijective XCD-aware swizzle over [0, G) ----
  int lin = blockIdx.x;
  int G = gridDim.x;
  int r8 = lin & 7, s8 = lin >> 3;
  int q = G >> 3, rem = G & 7;
  int start = r8 * q + (r8 < rem ? r8 : rem);
  int idx = start + s8;
  int tiles = Mt * Nt;
  int ks = 0;
  if (ksn > 1) { ks = idx / tiles; idx -= ks * tiles; }
  int mt, nt;
  if (mmaj) { mt = idx / Nt; nt = idx - mt * Nt; }
  else      { nt = idx / Mt; mt = idx - nt * Mt; }
  int m0 = mt * GBMv, n0 = nt * GBNv;
  int kper = K / ksn;
  int kbeg = ks * kper, kend = kbeg + kper;

  int wid = tid >> 6, lane = tid & 63;
  int wm = wid & 1, wn = wid >> 1;       // 2 M-waves x 2 N-waves
  int m16 = lane & 15, quad = lane >> 4;

  if constexpr (GBKT == 64) {
    // ================= 64x64x64 path (ASRC=1 only) =================
    f32x4 acc[2][2] = {};
    // staging: per plane, wave wid covers rows [wid*16, wid*16+16), 2 calls of 8 rows
    int rowg = lane >> 3;                 // 0..7 in call group
    int colb = (lane & 7) << 4;           // byte col 0..112 (linear)
    int scb  = colb ^ (rowg << 4);        // pre-swizzled source col
    int gr0  = (wid << 4) + rowg;         // tile row, call 0 (call 1 = +8)
    int a0 = m0 + gr0;      if (a0 >= M) a0 = M - 1;
    int a1 = m0 + gr0 + 8;  if (a1 >= M) a1 = M - 1;
    size_t ao0 = ((size_t)a0 * Ald) * 2 + scb;
    size_t ao1 = ((size_t)a1 * Ald) * 2 + scb;
    size_t bo0 = ((size_t)(n0 + gr0) * K) * 2 + scb;
    size_t bo1 = bo0 + (size_t)8 * K * 2;
    char* lA = (char*)Ash + (wid << 11);  // wid*16 rows * 128B
    char* la = (char*)Asl + (wid << 11);
    char* lB = (char*)Bsh + (wid << 11);
    char* lb = (char*)Bsl + (wid << 11);
    int fswz = (m16 & 7) << 4;            // read-side XOR (bytes)

    for (int k0 = kbeg; k0 < kend; k0 += 64) {
      size_t kb = (size_t)k0 * 2;
      gload16((const char*)Bh + bo0 + kb, lB);
      gload16((const char*)Bh + bo1 + kb, lB + 1024);
      gload16((const char*)Bl + bo0 + kb, lb);
      gload16((const char*)Bl + bo1 + kb, lb + 1024);
      gload16((const char*)Ah + ao0 + kb, lA);
      gload16((const char*)Ah + ao1 + kb, lA + 1024);
      gload16((const char*)Al + ao0 + kb, la);
      gload16((const char*)Al + ao1 + kb, la + 1024);
      __syncthreads();
      short8 ah[2][2], al2[2][2], bh[2][2], bl[2][2];  // [kk][frag]
#pragma unroll
      for (int kk = 0; kk < 2; kk++) {
        int cb = (kk << 6) + (quad << 4);              // byte col want
#pragma unroll
        for (int i = 0; i < 2; i++) {
          int ra = ((wm << 5) + (i << 4) + m16) * 128 + (cb ^ fswz);
          ah[kk][i]  = *(short8*)((char*)Ash + ra);
          al2[kk][i] = *(short8*)((char*)Asl + ra);
          int rb = ((wn << 5) + (i << 4) + m16) * 128 + (cb ^ fswz);
          bh[kk][i] = *(short8*)((char*)Bsh + rb);
          bl[kk][i] = *(short8*)((char*)Bsl + rb);
        }
      }
      __builtin_amdgcn_s_setprio(1);
#pragma unroll
      for (int kk = 0; kk < 2; kk++)
#pragma unroll
        for (int i = 0; i < 2; i++)
#pragma unroll
          for (int j = 0; j < 2; j++) {
            acc[i][j] = __builtin_amdgcn_mfma_f32_16x16x32_bf16(ah[kk][i], bh[kk][j], acc[i][j], 0, 0, 0);
            acc[i][j] = __builtin_amdgcn_mfma_f32_16x16x32_bf16(al2[kk][i], bh[kk][j], acc[i][j], 0, 0, 0);
            acc[i][j] = __builtin_amdgcn_mfma_f32_16x16x32_bf16(ah[kk][i], bl[kk][j], acc[i][j], 0, 0, 0);
          }
      __builtin_amdgcn_s_setprio(0);
      __syncthreads();
    }
    // epilogue (wave tile 32x32)
#pragma unroll
    for (int i = 0; i < 2; i++) {
#pragma unroll
      for (int j = 0; j < 2; j++) {
        int colg = n0 + (wn << 5) + (j << 4) + m16;
#pragma unroll
        for (int rr = 0; rr < 4; rr++) {
          int rowg2 = m0 + (wm << 5) + (i << 4) + (quad << 2) + rr;
          if (rowg2 >= M) continue;
          float v = acc[i][j][rr];
          if ((EPI & E_BIAS) && ks == 0) v += bias[colg];
          if (EPI & E_GELU) v = 0.5f * v * (1.0f + erff(v * 0.70710678118654752f));
          size_t off = (size_t)rowg2 * Cld + coff + colg;
          if (EPI & E_SPLK) {
            atomicAdd(&C[off], v);
          } else if (EPI & E_OUTS) {
            ushortT h, l; split2(v, h, l);
            Coh[off] = h; Col[off] = l;
          } else {
            if (EPI & E_ACC) v += C[off];
            C[off] = v;
          }
        }
      }
    }
    return;
  } else {
  // ================= GBK=32 path (R6-proven) =================
  f32x4 acc[WMF][4] = {};

  int gcb = (lane & 3) << 4;                       // byte col within 64B row
  int growB = (wid << 5) + (lane >> 2);
  int scbB  = gcb ^ (((growB >> 1) & 3) << 4);     // swz(row+16)==swz(row)
  char* ldsB = (char*)Bsh + (wid << 11);
  char* ldsb = (char*)Bsl + (wid << 11);
  size_t bo0 = ((size_t)(n0 + growB) * K) * 2 + scbB;
  size_t bo1 = bo0 + (size_t)16 * K * 2;
  int growA = wid * ARPW + (lane >> 2);
  int scbA  = gcb ^ (((growA >> 1) & 3) << 4);
  char* ldsA = (char*)Ash + wid * ARPW * 64;
  char* ldsa = (char*)Asl + wid * ARPW * 64;
  size_t ao0 = 0, ao1 = 0;
  if (ASRC == 1) {
    int ar0 = m0 + growA;  if (ar0 >= M) ar0 = M - 1;
    ao0 = ((size_t)ar0 * Ald) * 2 + scbA;
    if (ARPW == 32) {
      int ar1 = m0 + growA + 16;  if (ar1 >= M) ar1 = M - 1;
      ao1 = ((size_t)ar1 * Ald) * 2 + scbA;
    }
  }

  int srow = tid / TPR;
  int sseg = (tid % TPR) * EPT;
  int sswz = ((srow >> 1) & 3) << 3;

  int fswz = ((m16 >> 1) & 3) << 3;
  int scf  = (quad << 3) ^ fswz;

  for (int k0 = kbeg; k0 < kend; k0 += GBK) {
    size_t kb = (size_t)k0 * 2;
    gload16((const char*)Bh + bo0 + kb, ldsB);
    gload16((const char*)Bh + bo1 + kb, ldsB + 1024);
    gload16((const char*)Bl + bo0 + kb, ldsb);
    gload16((const char*)Bl + bo1 + kb, ldsb + 1024);
    if (ASRC == 1) {
      gload16((const char*)Ah + ao0 + kb, ldsA);
      gload16((const char*)Al + ao0 + kb, ldsa);
      if (ARPW == 32) {
        gload16((const char*)Ah + ao1 + kb, ldsA + 1024);
        gload16((const char*)Al + ao1 + kb, ldsa + 1024);
      }
    } else {
      int row = m0 + srow;
      if (row >= M) row = M - 1;
      float tf[EPT];
      if (AMODE == 0) {
        const float* p = A + (size_t)row * Ald + k0 + sseg;
#pragma unroll
        for (int j = 0; j < EPT; j += 4) {
          float4 v = *(const float4*)(p + j);
          tf[j] = v.x; tf[j+1] = v.y; tf[j+2] = v.z; tf[j+3] = v.w;
        }
      } else if (AMODE == 1) {
        int t = row % Tdim;
        const float* p = A + (size_t)row * Ald + k0 + sseg;
#pragma unroll
        for (int j = 0; j < EPT; j += 4) {
          float4 v = *(const float4*)(p + j);
          float4 w = (t != 0) ? *(const float4*)(p - Ald + j) : v;
          tf[j] = v.x - w.x; tf[j+1] = v.y - w.y;
          tf[j+2] = v.z - w.z; tf[j+3] = v.w - w.w;
        }
      } else {   // tap-major conv; tap uniform over this EPT-seg (Kin%EPT==0)
        int kk = k0 + sseg;
        int tap = kk / Kin;
        int i0  = kk - tap * Kin;
        int bb = row / Tdim;
        int t  = row - bb * Tdim;
        int tt = t - lo + tap;
        if (tt >= 0 && tt < Tdim) {
          const float* p = A + ((size_t)bb * Tdim + tt) * Ald + i0;
#pragma unroll
          for (int j = 0; j < EPT; j += 4) {
            float4 v = *(const float4*)(p + j);
            tf[j] = v.x; tf[j+1] = v.y; tf[j+2] = v.z; tf[j+3] = v.w;
          }
        } else {
#pragma unroll
          for (int j = 0; j < EPT; j++) tf[j] = 0.0f;
        }
      }
      ushortT th[EPT], tl[EPT];
#pragma unroll
      for (int j = 0; j < EPT; j++) split2(tf[j], th[j], tl[j]);
#pragma unroll
      for (int c8 = 0; c8 < EPT / 8; c8++) {
        int st = srow * GBK + ((sseg + c8 * 8) ^ sswz);
        *(ushort8*)&Ash[st] = *(ushort8*)&th[c8 * 8];
        *(ushort8*)&Asl[st] = *(ushort8*)&tl[c8 * 8];
      }
    }
    __syncthreads();
    short8 ah[WMF], al[WMF], bh[4], bl[4];
#pragma unroll
    for (int i = 0; i < WMF; i++) {
      int ro = (wm * (WMF * 16) + i * 16 + m16) * GBK + scf;
      ah[i] = *(short8*)&Ash[ro];
      al[i] = *(short8*)&Asl[ro];
    }
#pragma unroll
    for (int j = 0; j < 4; j++) {
      int ro = (wn * 64 + j * 16 + m16) * GBK + scf;
      bh[j] = *(short8*)&Bsh[ro];
      bl[j] = *(short8*)&Bsl[ro];
    }
    __builtin_amdgcn_s_setprio(1);
#pragma unroll
    for (int i = 0; i < WMF; i++)
#pragma unroll
      for (int j = 0; j < 4; j++) {
        acc[i][j] = __builtin_amdgcn_mfma_f32_16x16x32_bf16(ah[i], bh[j], acc[i][j], 0, 0, 0);
        acc[i][j] = __builtin_amdgcn_mfma_f32_16x16x32_bf16(al[i], bh[j], acc[i][j], 0, 0, 0);
        acc[i][j] = __builtin_amdgcn_mfma_f32_16x16x32_bf16(ah[i], bl[j], acc[i][j], 0, 0, 0);
      }
    __builtin_amdgcn_s_setprio(0);
    __syncthreads();
  }

#pragma unroll
  for (int i = 0; i < WMF; i++) {
#pragma unroll
    for (int j = 0; j < 4; j++) {
      int colg = n0 + wn * 64 + j * 16 + m16;
#pragma unroll
      for (int rr = 0; rr < 4; rr++) {
        int rowg = m0 + wm * (WMF * 16) + i * 16 + quad * 4 + rr;
        if (rowg >= M) continue;
        float v = acc[i][j][rr];
        if ((EPI & E_BIAS) && ks == 0) v += bias[colg];
        if (EPI & E_PE)   v += extra[(size_t)(rowg % Tdim) * N + colg];
        if (EPI & E_RES)  v += extra[(size_t)rowg * Cld + colg];
        if (EPI & E_GELU) v = 0.5f * v * (1.0f + erff(v * 0.70710678118654752f));
        size_t off = (size_t)rowg * Cld + coff + colg;
        if (EPI & E_SPLK) {
          atomicAdd(&C[off], v);
        } else if (EPI & E_OUTS) {
          ushortT h, l; split2(v, h, l);
          Coh[off] = h; Col[off] = l;
        } else {
          if (EPI & E_ACC) v += C[off];
          C[off] = v;
        }
      }
    }
  }
  }
}

#define GEMM3(BMS_, GBK_, AM, AS, EP, KS, Asrc, AhP, AlP, BhP, BlP, biasP, extraP, CP, CohP, ColP, \
              Mv, Nv, Kv, AldV, TdimV, loV, KinV, CldV, coffV) \
  do { int Mt_ = ((Mv) + (BMS_) - 1) / (BMS_); \
       int Nt_ = (Nv) / (((GBK_) == 64) ? 64 : 128); \
       int mm_ = ((Mv) >= (Nv)) ? 1 : 0; \
       gemm3<BMS_, GBK_, AM, AS, EP><<<dim3(Mt_ * Nt_ * (KS)), dim3(256), 0, stream>>>( \
           Asrc, AhP, AlP, BhP, BlP, biasP, extraP, CP, CohP, ColP, \
           Mv, Nv, Kv, AldV, TdimV, loV, KinV, CldV, coffV, Mt_, Nt_, mm_, KS); } while (0)

// ====== weight transpose + split: fp32 [K][N] -> bf16 hi/lo [N][K] ======
__global__ __launch_bounds__(256) void wcvt_t_split(
    const float* __restrict__ W, ushortT* __restrict__ Wh, ushortT* __restrict__ Wl,
    int K, int N)
{
  __shared__ float t[32][33];
  int k0 = blockIdx.y * 32, n0 = blockIdx.x * 32;
  int tx = threadIdx.x;
  int ty = threadIdx.y;
#pragma unroll
  for (int dy = 0; dy < 32; dy += 8)
    t[ty + dy][tx] = W[(size_t)(k0 + ty + dy) * N + n0 + tx];
  __syncthreads();
#pragma unroll
  for (int dy = 0; dy < 32; dy += 8) {
    float v = t[tx][ty + dy];
    ushortT h, l;
    split2(v, h, l);
    size_t off = (size_t)(n0 + ty + dy) * K + k0 + tx;
    Wh[off] = h; Wl[off] = l;
  }
}

// ====== flat split: fp32 -> bf16 hi/lo ======
__global__ __launch_bounds__(256) void wcvt_split(
    const float* __restrict__ W, ushortT* __restrict__ Wh, ushortT* __restrict__ Wl, int n)
{
  int gid = blockIdx.x * 256 + threadIdx.x;
  int stride = gridDim.x * 256;
  for (int i = gid; i < n; i += stride) {
    ushortT h, l;
    split2(W[i], h, l);
    Wh[i] = h; Wl[i] = l;
  }
}

// ====== conv weight split, tap-major: [O][Kin][NT] -> [O][NT*Kin] ======
__global__ __launch_bounds__(256) void wcvt_split_tm(
    const float* __restrict__ W, ushortT* __restrict__ Wh, ushortT* __restrict__ Wl,
    int O, int Kin, int NT)
{
  int n = O * Kin * NT;
  int gid = blockIdx.x * 256 + threadIdx.x;
  int stride = gridDim.x * 256;
  for (int idx = gid; idx < n; idx += stride) {
    int o = idx / (Kin * NT);
    int rr = idx - o * (Kin * NT);
    int tap = rr / Kin;
    int i = rr - tap * Kin;
    float v = W[(size_t)o * Kin * NT + (size_t)i * NT + tap];
    ushortT h, l;
    split2(v, h, l);
    Wh[idx] = h; Wl[idx] = l;
  }
}

// =================== fp32 fallback GEMM (classifier only) ===================
constexpr int BM = 64, BN = 64, BK = 16, TM = 4, TN = 4;
__global__ __launch_bounds__(256) void gemm_cls(
    const float* __restrict__ A, const float* __restrict__ Bw,
    const float* __restrict__ bias, float* __restrict__ C,
    int M, int N, int K, int Ald, int Cld)
{
  __shared__ alignas(16) float As[BK][BM + 4];
  __shared__ alignas(16) float Bs[BK][BN + 4];
  int tid = threadIdx.x;
  int n0 = blockIdx.x * BN;
  int m0 = blockIdx.y * BM;
  int tx = tid & 15, ty = tid >> 4;
  float acc[TM][TN];
#pragma unroll
  for (int i = 0; i < TM; i++)
#pragma unroll
    for (int j = 0; j < TN; j++) acc[i][j] = 0.0f;
  int a_m = tid >> 2, a_k = (tid & 3) * 4;
  int b_k = tid >> 4, b_n = (tid & 15) * 4;
  for (int k0 = 0; k0 < K; k0 += BK) {
    int row = m0 + a_m;
#pragma unroll
    for (int j = 0; j < 4; j++)
      As[a_k + j][a_m] = A[(size_t)row * Ald + k0 + a_k + j];
    int kk = k0 + b_k;
#pragma unroll
    for (int j = 0; j < 4; j++) {
      int nn = n0 + b_n + j;
      Bs[b_k][b_n + j] = (nn < N) ? Bw[(size_t)kk * N + nn] : 0.0f;
    }
    __syncthreads();
#pragma unroll
    for (int k = 0; k < BK; k++) {
      float4 av = *reinterpret_cast<const float4*>(&As[k][ty * TM]);
      float4 bv = *reinterpret_cast<const float4*>(&Bs[k][tx * TN]);
      float a4[4] = {av.x, av.y, av.z, av.w};
      float b4[4] = {bv.x, bv.y, bv.z, bv.w};
#pragma unroll
      for (int i = 0; i < TM; i++)
#pragma unroll
        for (int j = 0; j < TN; j++) acc[i][j] += a4[i] * b4[j];
    }
    __syncthreads();
  }
#pragma unroll
  for (int i = 0; i < TM; i++) {
    int row = m0 + ty * TM + i;
#pragma unroll
    for (int j = 0; j < TN; j++) {
      int col = n0 + tx * TN + j;
      if (col >= N) continue;
      C[(size_t)row * Cld + col] = acc[i][j] + bias[col];
    }
  }
}

// ---- rfft over 48 tokens, real part (fp32) ----
__global__ __launch_bounds__(256) void rfft48_kernel(
    const float* __restrict__ hp, float* __restrict__ f)
{
  int kf = blockIdx.x;
  int b  = blockIdx.y;
  int tid = threadIdx.x;
  __shared__ float ct[48];
  if (tid < 48) {
    int rr = (kf * tid) % 48;
    ct[tid] = cosf(6.2831853071795864f * (float)rr / 48.0f);
  }
  __syncthreads();
  const float* hb = hp + (size_t)b * Tp * Hd;
  float s = 0.0f;
  for (int t = 0; t < 48; t++) s += hb[t * Hd + tid] * ct[t];
  f[((size_t)b * Ff + kf) * Hd + tid] = s;
}

// ---- fused fourier attention: logits -> softmax -> circulant(G) @ v ----
__global__ __launch_bounds__(256) void attn_fused(
    const float* __restrict__ qkv,     // chunk [nb*25, 2304]
    ushortT* __restrict__ oh, ushortT* __restrict__ ol)
{
  int bh = blockIdx.x;
  int b = bh >> 3, h = bh & 7;
  __shared__ float qs[Ff * DH], ks[Ff * DH], vs[Ff * DH];
  __shared__ float ct[F2 * Ff], st[F2 * Ff];
  __shared__ float red[F2 * DH];
  __shared__ float sm[F2];
  __shared__ float G[Ff];
  int tid = threadIdx.x;
  const float* base = qkv + (size_t)b * Ff * (3 * Ed) + h * DH;
  for (int e = tid; e < Ff * DH; e += 256) {
    int t = e / DH, d = e - t * DH;
    size_t ro = (size_t)t * (3 * Ed) + d;
    qs[e] = base[ro];
    ks[e] = base[ro + Ed];
    vs[e] = base[ro + 2 * Ed];
  }
  for (int e = tid; e < F2 * Ff; e += 256) {
    int fq = e / Ff, t = e - fq * Ff;
    int rr = (fq * t) % Ff;
    float ang = 6.2831853071795864f * (float)rr / 25.0f;
    ct[e] = cosf(ang); st[e] = sinf(ang);
  }
  __syncthreads();
  for (int e = tid; e < F2 * DH; e += 256) {
    int fq = e / DH, d = e - fq * DH;
    float qr = 0, qi = 0, kr = 0, ki = 0;
    for (int t = 0; t < Ff; t++) {
      float c = ct[fq * Ff + t], s = st[fq * Ff + t];
      float qv = qs[t * DH + d], kv = ks[t * DH + d];
      qr += qv * c; qi += qv * s; kr += kv * c; ki += kv * s;
    }
    red[e] = qr * kr + qi * ki;
  }
  __syncthreads();
  if (tid < F2) {
    float s = 0;
    for (int d = 0; d < DH; d++) s += red[tid * DH + d];
    sm[tid] = s * 0.10206207261596575f;  // 96^-0.5
  }
  __syncthreads();
  if (tid == 0) {
    float mx = sm[0];
    for (int f = 1; f < F2; f++) mx = fmaxf(mx, sm[f]);
    float den = 0;
    for (int f = 0; f < F2; f++) { float e2 = expf(sm[f] - mx); sm[f] = e2; den += e2; }
    float inv = 1.0f / den;
    for (int f = 0; f < F2; f++)
      sm[f] *= inv * ((f == 0) ? (1.0f / 25.0f) : (2.0f / 25.0f));
  }
  __syncthreads();
  if (tid < Ff) {
    float g = 0;
    for (int f = 0; f < F2; f++) g += sm[f] * ct[f * Ff + tid];
    G[tid] = g;
  }
  __syncthreads();
  size_t ob = ((size_t)b * Ff) * Ed + h * DH;
  for (int e = tid; e < Ff * DH; e += 256) {
    int t = e / DH, d = e - t * DH;
    float o = 0;
    int dd = t;
    for (int tp = 0; tp < Ff; tp++) {
      o += G[dd] * vs[tp * DH + d];
      dd--; if (dd < 0) dd += Ff;
    }
    ushortT hh, ll;
    split2(o, hh, ll);
    size_t off = ob + (size_t)t * Ed + d;
    oh[off] = hh; ol[off] = ll;
  }
}

// ---- layernorm over 768: shuffle-reduce (2 barriers) ----
static __device__ __forceinline__ float wave_sum(float s) {
#pragma unroll
  for (int o = 32; o > 0; o >>= 1) s += __shfl_xor(s, o);
  return s;
}

__global__ __launch_bounds__(256) void ln_split(
    const float* __restrict__ x, const float* __restrict__ g,
    const float* __restrict__ bb, ushortT* __restrict__ yh, ushortT* __restrict__ yl)
{
  int row = blockIdx.x;
  int tid = threadIdx.x;
  int wid = tid >> 6, lane = tid & 63;
  const float* xr = x + (size_t)row * Ed;
  float v0 = xr[tid], v1 = xr[tid + 256], v2 = xr[tid + 512];
  __shared__ float wsum[4], wsq[4];
  float s = wave_sum(v0 + v1 + v2);
  if (lane == 0) wsum[wid] = s;
  __syncthreads();
  float m = (wsum[0] + wsum[1] + wsum[2] + wsum[3]) * (1.0f / 768.0f);
  float d0 = v0 - m, d1 = v1 - m, d2 = v2 - m;
  float q = wave_sum(d0 * d0 + d1 * d1 + d2 * d2);
  if (lane == 0) wsq[wid] = q;
  __syncthreads();
  float inv = rsqrtf((wsq[0] + wsq[1] + wsq[2] + wsq[3]) * (1.0f / 768.0f) + 1e-5f);
  size_t basei = (size_t)row * Ed;
  float o0 = d0 * inv * g[tid] + bb[tid];
  float o1 = d1 * inv * g[tid + 256] + bb[tid + 256];
  float o2 = d2 * inv * g[tid + 512] + bb[tid + 512];
  ushortT h, l;
  split2(o0, h, l); yh[basei + tid] = h;       yl[basei + tid] = l;
  split2(o1, h, l); yh[basei + tid + 256] = h; yl[basei + tid + 256] = l;
  split2(o2, h, l); yh[basei + tid + 512] = h; yl[basei + tid + 512] = l;
}

__global__ __launch_bounds__(256) void ln_f32(
    const float* __restrict__ x, const float* __restrict__ g,
    const float* __restrict__ bb, float* __restrict__ y)
{
  int row = blockIdx.x;
  int tid = threadIdx.x;
  int wid = tid >> 6, lane = tid & 63;
  const float* xr = x + (size_t)row * Ed;
  float v0 = xr[tid], v1 = xr[tid + 256], v2 = xr[tid + 512];
  __shared__ float wsum[4], wsq[4];
  float s = wave_sum(v0 + v1 + v2);
  if (lane == 0) wsum[wid] = s;
  __syncthreads();
  float m = (wsum[0] + wsum[1] + wsum[2] + wsum[3]) * (1.0f / 768.0f);
  float d0 = v0 - m, d1 = v1 - m, d2 = v2 - m;
  float q = wave_sum(d0 * d0 + d1 * d1 + d2 * d2);
  if (lane == 0) wsq[wid] = q;
  __syncthreads();
  float inv = rsqrtf((wsq[0] + wsq[1] + wsq[2] + wsq[3]) * (1.0f / 768.0f) + 1e-5f);
  float* yr = y + (size_t)row * Ed;
  yr[tid]       = d0 * inv * g[tid]       + bb[tid];
  yr[tid + 256] = d1 * inv * g[tid + 256] + bb[tid + 256];
  yr[tid + 512] = d2 * inv * g[tid + 512] + bb[tid + 512];
}

// ---- mean over 25 tokens ----
__global__ __launch_bounds__(256) void mean_kernel(
    const float* __restrict__ x, float* __restrict__ y)
{
  int b = blockIdx.x;
  int tid = threadIdx.x;
  for (int c = tid; c < Ed; c += 256) {
    float s = 0;
    for (int t = 0; t < Ff; t++) s += x[((size_t)b * Ff + t) * Ed + c];
    y[(size_t)b * Ed + c] = s * (1.0f / 25.0f);
  }
}

extern "C" void kernel_launch(void* const* d_in, const int* in_sizes, int n_in,
                              void* d_out, int out_size, void* d_ws, size_t ws_size,
                              hipStream_t stream)
{
  const float* x       = (const float*)d_in[0];
  const float* W_in    = (const float*)d_in[1];
  const float* b_in    = (const float*)d_in[2];
  const float* pe      = (const float*)d_in[3];
  const float* W_shape = (const float*)d_in[4];
  const float* b_shape = (const float*)d_in[5];
  const float* W_patch = (const float*)d_in[6];
  const float* b_patch = (const float*)d_in[7];
  const float* conv_w1 = (const float*)d_in[8];
  const float* conv_b1 = (const float*)d_in[9];
  const float* conv_w2 = (const float*)d_in[10];
  const float* conv_b2 = (const float*)d_in[11];
  const float* conv_w4 = (const float*)d_in[12];
  const float* conv_b4 = (const float*)d_in[13];
  const float* ln1_g   = (const float*)d_in[14];
  const float* ln1_b   = (const float*)d_in[15];
  const float* Wqkv    = (const float*)d_in[16];
  const float* Wo      = (const float*)d_in[17];
  const float* bo      = (const float*)d_in[18];
  const float* ln2_g   = (const float*)d_in[19];
  const float* ln2_b   = (const float*)d_in[20];
  const float* Wf1     = (const float*)d_in[21];
  const float* bf1     = (const float*)d_in[22];
  const float* Wf2     = (const float*)d_in[23];
  const float* bf2     = (const float*)d_in[24];
  const float* ssm_w   = (const float*)d_in[25];
  const float* ssm_b   = (const float*)d_in[26];
  const float* ssm_g   = (const float*)d_in[27];
  const float* ssm_bn  = (const float*)d_in[28];
  const float* W_out   = (const float*)d_in[29];
  const float* b_out   = (const float*)d_in[30];
  float* out = (float*)d_out;

  // ---- workspace: h 39.3MB | planes 39.3MB | pool 44.0MB = 122.7MB ----
  float* hbuf = (float*)d_ws;                    // 9,830,400 fl
  ushortT* Ahp = (ushortT*)(hbuf + 9830400);     // 9,830,400 slots
  ushortT* Alp = Ahp + 9830400;                  // 9,830,400 slots
  float* pool = (float*)(Alp + 9830400);         // 11,010,048 fl

  dim3 blk(256);
  dim3 wblk(32, 8);
  const int Mf = Bsz * Ff;   // 12800
  const ushortT* NUS = nullptr;
  const float* NF = nullptr;
  ushortT* NU = nullptr;

  // ---------------- phase-0 weights (pool + 6,291,456 fl) ----------------
  ushortT* p0w = (ushortT*)(pool + 6291456);
  ushortT* WinH = p0w + 0;        ushortT* WinL = p0w + 16384;
  ushortT* WshH = p0w + 32768;    ushortT* WshL = p0w + 98304;
  ushortT* WpaH = p0w + 163840;   ushortT* WpaL = p0w + 294912;
  ushortT* c1H  = p0w + 425984;   ushortT* c1L  = p0w + 491520;
  ushortT* c2H  = p0w + 557056;   ushortT* c2L  = p0w + 688128;
  ushortT* c4H  = p0w + 819200;   ushortT* c4L  = p0w + 1081344;
  wcvt_t_split<<<dim3(Hd / 32, DIN / 32), wblk, 0, stream>>>(W_in, WinH, WinL, DIN, Hd);
  wcvt_t_split<<<dim3(Hd / 32, Hd / 32), wblk, 0, stream>>>(W_shape, WshH, WshL, Hd, Hd);
  wcvt_t_split<<<dim3(Hd / 32, (Pp * Hd) / 32), wblk, 0, stream>>>(W_patch, WpaH, WpaL, Pp * Hd, Hd);
  wcvt_split<<<64, blk, 0, stream>>>(conv_w1, c1H, c1L, Hd * Hd);
  wcvt_split_tm<<<128, blk, 0, stream>>>(conv_w2, c2H, c2L, Hd, Hd, 2);
  wcvt_split_tm<<<256, blk, 0, stream>>>(conv_w4, c4H, c4L, Hd, Hd, 4);

  // ---------------- phase 0: 2 chunks of 256 batches ----------------
  float* s0  = (float*)Ahp;
  float* s1f = (float*)Ahp + 6291456;
  float* s1  = pool;
  for (int c = 0; c < 2; c++) {
    const int NB = 256;
    const int M96 = NB * Tin;      // 24576
    const int Mpch = NB * Tp;      // 12288
    const float* xc = x + (size_t)c * NB * Tin * DIN;

    GEMM3(64, 32, 0, 0, E_BIAS | E_PE, 1, xc, NUS, NUS, WinH, WinL, b_in, pe, s0, NU, NU,
          M96, Hd, DIN, DIN, Tin, 0, 0, Hd, 0);
    GEMM3(64, 32, 1, 0, E_BIAS | E_RES, 1, s0, NUS, NUS, WshH, WshL, b_shape, s0, s1, NU, NU,
          M96, Hd, Hd, Hd, Tin, 0, 0, Hd, 0);
    GEMM3(64, 32, 0, 0, E_BIAS, 1, s1, NUS, NUS, WpaH, WpaL, b_patch, NF, s0, NU, NU,
          Mpch, Hd, Pp * Hd, Pp * Hd, 0, 0, 0, Hd, 0);
    rfft48_kernel<<<dim3(Ff, NB), blk, 0, stream>>>(s0, s1f + (size_t)c * NB * Ff * Hd);
  }
  // conv GEMMs over all 12800 rows at once
  GEMM3(64, 32, 0, 0, E_BIAS, 1, s1f, NUS, NUS, c1H, c1L, conv_b1, NF, hbuf, NU, NU,
        Mf, Hd, Hd, Hd, Ff, 0, 0, Ed, 0);
  GEMM3(64, 32, 2, 0, E_BIAS, 1, s1f, NUS, NUS, c2H, c2L, conv_b2, NF, hbuf, NU, NU,
        Mf, Hd, Hd * 2, Hd, Ff, 0, Hd, Ed, Hd);
  GEMM3(64, 32, 2, 0, E_BIAS, 1, s1f, NUS, NUS, c4H, c4L, conv_b4, NF, hbuf, NU, NU,
        Mf, Hd, Hd * 4, Hd, Ff, 1, Hd, Ed, 2 * Hd);

  // ---------------- transformer layers ----------------
  float* qkvbuf = pool;                          // 7,372,800 fl (chunk 3200x2304)
  ushortT* lwA = (ushortT*)(pool + 7372800);
  ushortT* qkH = lwA + 0;        ushortT* qkL = lwA + 1769472;
  ushortT* woH = lwA + 3538944;  ushortT* woL = lwA + 4128768;
  ushortT* Ch2 = (ushortT*)pool;                 // ffmid hi (2048x3072)
  ushortT* Cl2 = Ch2 + 6291456;                  // ffmid lo
  ushortT* lwB = (ushortT*)(pool + 6291456);
  ushortT* f1H = lwB + 0;        ushortT* f1L = lwB + 2359296;
  ushortT* f2H = lwB + 4718592;  ushortT* f2L = lwB + 7077888;

  const int NBA = 128;           // batches per attention chunk (4 chunks)
  const int Mca = NBA * Ff;      // 3200 rows

  for (int l = 0; l < Ll; l++) {
    const float* Wqkv_l = Wqkv + (size_t)l * Ed * (3 * Ed);
    const float* Wo_l   = Wo   + (size_t)l * Ed * Ed;
    const float* bo_l   = bo   + (size_t)l * Ed;
    const float* Wf1_l  = Wf1  + (size_t)l * Ed * (4 * Ed);
    const float* bf1_l  = bf1  + (size_t)l * (4 * Ed);
    const float* Wf2_l  = Wf2  + (size_t)l * (4 * Ed) * Ed;
    const float* bf2_l  = bf2  + (size_t)l * Ed;

    wcvt_t_split<<<dim3((3 * Ed) / 32, Ed / 32), wblk, 0, stream>>>(Wqkv_l, qkH, qkL, Ed, 3 * Ed);
    wcvt_t_split<<<dim3(Ed / 32, Ed / 32), wblk, 0, stream>>>(Wo_l, woH, woL, Ed, Ed);

    ln_split<<<Mf, blk, 0, stream>>>(hbuf, ln1_g + (size_t)l * Ed, ln1_b + (size_t)l * Ed, Ahp, Alp);

    for (int c = 0; c < 4; c++) {
      ushortT* ah = Ahp + (size_t)c * Mca * Ed;
      ushortT* al = Alp + (size_t)c * Mca * Ed;
      GEMM3(64, 64, 0, 1, 0, 1, NF, ah, al, qkH, qkL, NF, NF, qkvbuf, NU, NU,
            Mca, 3 * Ed, Ed, Ed, 0, 0, 0, 3 * Ed, 0);
      attn_fused<<<NBA * NHEAD, blk, 0, stream>>>(qkvbuf, ah, al);
    }
    // Wo: 64x64x64 drain-halved tile + split-K=2
    GEMM3(64, 64, 0, 1, E_BIAS | E_SPLK, 2, NF, Ahp, Alp, woH, woL, bo_l, NF, hbuf, NU, NU,
          Mf, Ed, Ed, Ed, 0, 0, 0, Ed, 0);

    wcvt_t_split<<<dim3((4 * Ed) / 32, Ed / 32), wblk, 0, stream>>>(Wf1_l, f1H, f1L, Ed, 4 * Ed);
    wcvt_t_split<<<dim3(Ed / 32, (4 * Ed) / 32), wblk, 0, stream>>>(Wf2_l, f2H, f2L, 4 * Ed, Ed);

    ln_split<<<Mf, blk, 0, stream>>>(hbuf, ln2_g + (size_t)l * Ed, ln2_b + (size_t)l * Ed, Ahp, Alp);

    for (int row0 = 0; row0 < Mf; row0 += 2048) {
      int rows = (Mf - row0 < 2048) ? (Mf - row0) : 2048;
      GEMM3(64, 64, 0, 1, E_BIAS | E_GELU | E_OUTS, 1, NF,
            Ahp + (size_t)row0 * Ed, Alp + (size_t)row0 * Ed, f1H, f1L, bf1_l, NF,
            (float*)nullptr, Ch2, Cl2, rows, 4 * Ed, Ed, Ed, 0, 0, 0, 4 * Ed, 0);
      // split-K=4: K=3072 -> 4x768, fp32 atomic accumulate onto residual in hbuf
      GEMM3(64, 64, 0, 1, E_BIAS | E_SPLK, 4, NF, Ch2, Cl2, f2H, f2L, bf2_l, NF,
            hbuf + (size_t)row0 * Ed, NU, NU, rows, Ed, 4 * Ed, 4 * Ed, 0, 0, 0, Ed, 0);
    }
  }

  // ---------------- tail ----------------
  ushortT* ssH = (ushortT*)pool; ushortT* ssL = ssH + 1769472;
  wcvt_split_tm<<<512, blk, 0, stream>>>(ssm_w, ssH, ssL, Ed, Ed, 3);
  float* S = (float*)Ahp;   // h + s (plane area)
  GEMM3(128, 32, 2, 0, E_BIAS | E_RES, 1, hbuf, NUS, NUS, ssH, ssL, ssm_b, hbuf, S, NU, NU,
        Mf, Ed, Ed * 3, Ed, Ff, 1, Ed, Ed, 0);

  float* L = pool;          // final LN out (overwrites ssH, dead)
  ln_f32<<<Mf, blk, 0, stream>>>(S, ssm_g, ssm_bn, L);
  float* mout = (float*)Ahp;
  mean_kernel<<<Bsz, blk, 0, stream>>>(L, mout);
  gemm_cls<<<dim3(2, Bsz / BM), blk, 0, stream>>>(
      mout, W_out, b_out, out, Bsz, NCls, Ed, Ed, NCls);
}